// Round 1
// baseline (554.151 us; speedup 1.0000x reference)
//
#include <hip/hip_runtime.h>
#include <hip/hip_bf16.h>

// Qwen2VL vision block, MI355X gfx950.
// Pipeline: cvt weights -> LN1 -> QKV GEMM -> RoPE -> flash attn (block-diag) ->
//           proj GEMM (+residual) -> LN2 -> FC1 GEMM (+quickGELU) -> FC2 GEMM (+residual)
// All matmuls bf16 MFMA 16x16x32, fp32 accumulate.

typedef __bf16 bf16_t;
typedef bf16_t bf16x8 __attribute__((ext_vector_type(8)));
typedef bf16_t bf16x4 __attribute__((ext_vector_type(4)));
typedef float f32x4 __attribute__((ext_vector_type(4)));

#define DIM 1280
#define NHEADS 16
#define HDIM 80
#define MLP 5120
#define NTOK 4096
#define QKV_N 3840

// ---------------- fp32 -> bf16 conversion ----------------
__global__ void cvt_f32_bf16(const float* __restrict__ in, bf16_t* __restrict__ out, int n) {
    int i = (blockIdx.x * blockDim.x + threadIdx.x) * 4;
    int stride = gridDim.x * blockDim.x * 4;
    for (; i < n; i += stride) {
        float4 v = *(const float4*)(in + i);
        bf16x4 o;
        o[0] = (bf16_t)v.x; o[1] = (bf16_t)v.y; o[2] = (bf16_t)v.z; o[3] = (bf16_t)v.w;
        *(bf16x4*)(out + i) = o;
    }
}

// ---------------- segment ids from cu_seqlens ----------------
__global__ void seg_kernel(const int* __restrict__ cu, int ncu, int* __restrict__ seg, int n) {
    int i = blockIdx.x * blockDim.x + threadIdx.x;
    if (i >= n) return;
    int s = 0;
    for (int j = 1; j < ncu - 1; j++) if (i >= cu[j]) s = j;
    seg[i] = s;
}

// ---------------- LayerNorm (fp32 in, bf16 out), one block per row ----------------
__global__ __launch_bounds__(256) void ln_kernel(const float* __restrict__ x,
                                                 const float* __restrict__ w,
                                                 const float* __restrict__ b,
                                                 bf16_t* __restrict__ out) {
    int row = blockIdx.x;
    const float* xr = x + (long)row * DIM;
    float v[5];
    float s = 0.f, ss = 0.f;
#pragma unroll
    for (int j = 0; j < 5; j++) {
        v[j] = xr[j * 256 + threadIdx.x];
        s += v[j];
        ss += v[j] * v[j];
    }
#pragma unroll
    for (int off = 32; off > 0; off >>= 1) {
        s += __shfl_xor(s, off, 64);
        ss += __shfl_xor(ss, off, 64);
    }
    __shared__ float red[8];
    int wid = threadIdx.x >> 6;
    if ((threadIdx.x & 63) == 0) { red[wid] = s; red[wid + 4] = ss; }
    __syncthreads();
    s = red[0] + red[1] + red[2] + red[3];
    ss = red[4] + red[5] + red[6] + red[7];
    float mean = s * (1.f / DIM);
    float var = ss * (1.f / DIM) - mean * mean;
    float rstd = rsqrtf(var + 1e-6f);
    bf16_t* orow = out + (long)row * DIM;
#pragma unroll
    for (int j = 0; j < 5; j++) {
        int d = j * 256 + threadIdx.x;
        orow[d] = (bf16_t)((v[j] - mean) * rstd * w[d] + b[d]);
    }
}

// ---------------- RoPE in-place on bf16 qkv (q and k) ----------------
__global__ void rope_kernel(bf16_t* __restrict__ qkv, const float* __restrict__ rot, int n) {
    int i = blockIdx.x * blockDim.x + threadIdx.x;
    if (i >= n * NHEADS * 40) return;
    int d = i % 40;
    int hh = (i / 40) % NHEADS;
    int t = i / (40 * NHEADS);
    float r = rot[t * 40 + d];
    float c, sn;
    sincosf(r, &sn, &c);
    long base = (long)t * QKV_N + hh * HDIM;
#pragma unroll
    for (int part = 0; part < 2; part++) {
        bf16_t* p = qkv + base + part * DIM;
        float x1 = (float)p[d], x2 = (float)p[d + 40];
        p[d] = (bf16_t)(x1 * c - x2 * sn);
        p[d + 40] = (bf16_t)(x2 * c + x1 * sn);
    }
}

// ---------------- GEMM: C[M,N] = A[M,K] * B[N,K]^T + bias, epilogue variants ----
// EPI 0: out bf16 = acc + bias
// EPI 1: out f32  = res + acc + bias
// EPI 2: out bf16 = quick_gelu(acc + bias)
// 128x128 tile, BK=32, 4 waves (2x2), each wave 64x64 = 4x4 frags of 16x16x32.
template <int EPI>
__global__ __launch_bounds__(256) void gemm_bt(const bf16_t* __restrict__ A,
                                               const bf16_t* __restrict__ B,
                                               const float* __restrict__ bias,
                                               const float* __restrict__ res,
                                               void* __restrict__ Cv,
                                               int M, int N, int K) {
    __shared__ bf16_t lA[128 * 40];  // +8 pad breaks bank-conflict stride
    __shared__ bf16_t lB[128 * 40];
    const int tid = threadIdx.x;
    const int lane = tid & 63;
    const int l15 = lane & 15;
    const int g = lane >> 4;
    const int wid = tid >> 6;
    const int wr = wid >> 1, wc = wid & 1;
    const int m0 = blockIdx.y * 128, n0 = blockIdx.x * 128;

    f32x4 acc[4][4];
#pragma unroll
    for (int i = 0; i < 4; i++)
#pragma unroll
        for (int j = 0; j < 4; j++) acc[i][j] = (f32x4){0.f, 0.f, 0.f, 0.f};

    const int srow = tid >> 2;        // 0..63
    const int scol = (tid & 3) * 8;   // 0,8,16,24

    for (int k0 = 0; k0 < K; k0 += 32) {
        bf16x8 a0 = *(const bf16x8*)(A + (long)(m0 + srow) * K + k0 + scol);
        bf16x8 a1 = *(const bf16x8*)(A + (long)(m0 + srow + 64) * K + k0 + scol);
        bf16x8 b0 = *(const bf16x8*)(B + (long)(n0 + srow) * K + k0 + scol);
        bf16x8 b1 = *(const bf16x8*)(B + (long)(n0 + srow + 64) * K + k0 + scol);
        *(bf16x8*)(lA + srow * 40 + scol) = a0;
        *(bf16x8*)(lA + (srow + 64) * 40 + scol) = a1;
        *(bf16x8*)(lB + srow * 40 + scol) = b0;
        *(bf16x8*)(lB + (srow + 64) * 40 + scol) = b1;
        __syncthreads();

        const int kh = g * 8;
        bf16x8 af[4], bfr[4];
#pragma unroll
        for (int m = 0; m < 4; m++)
            af[m] = *(const bf16x8*)(lA + (wr * 64 + m * 16 + l15) * 40 + kh);
#pragma unroll
        for (int n = 0; n < 4; n++)
            bfr[n] = *(const bf16x8*)(lB + (wc * 64 + n * 16 + l15) * 40 + kh);
#pragma unroll
        for (int m = 0; m < 4; m++)
#pragma unroll
            for (int n = 0; n < 4; n++)
                acc[m][n] = __builtin_amdgcn_mfma_f32_16x16x32_bf16(af[m], bfr[n], acc[m][n], 0, 0, 0);
        __syncthreads();
    }

    // epilogue: D row = (lane>>4)*4 + r, col = lane&15 (measured m89 layout)
#pragma unroll
    for (int m = 0; m < 4; m++) {
#pragma unroll
        for (int n = 0; n < 4; n++) {
            int col = n0 + wc * 64 + n * 16 + l15;
            float bv = bias[col];
#pragma unroll
            for (int r = 0; r < 4; r++) {
                int row = m0 + wr * 64 + m * 16 + g * 4 + r;
                long idx = (long)row * N + col;
                float val = acc[m][n][r] + bv;
                if (EPI == 0) {
                    ((bf16_t*)Cv)[idx] = (bf16_t)val;
                } else if (EPI == 1) {
                    ((float*)Cv)[idx] = res[idx] + val;
                } else {
                    float ge = val / (1.f + __expf(-1.702f * val));
                    ((bf16_t*)Cv)[idx] = (bf16_t)ge;
                }
            }
        }
    }
}

// ---------------- Flash attention, block-diagonal mask ----------------
// Block = 4 waves, q-tile = 64 rows (wave w owns rows w*16..w*16+15), head = blockIdx.y.
// head_dim 80 zero-padded to 96 (3 MFMA K-steps). K tiles of 64 within q's segment range.
__global__ __launch_bounds__(256) void attn_kernel(const bf16_t* __restrict__ qkv,
                                                   const int* __restrict__ seg,
                                                   const int* __restrict__ cu,
                                                   bf16_t* __restrict__ out) {
    __shared__ bf16_t lK[64 * 96];      // [k][d padded]
    __shared__ bf16_t lV[80 * 64];      // transposed: [d][k]
    __shared__ bf16_t lP[4 * 16 * 64];  // per-wave P tile

    const int tid = threadIdx.x;
    const int lane = tid & 63;
    const int l15 = lane & 15;
    const int g = lane >> 4;
    const int wid = tid >> 6;
    const int h = blockIdx.y;
    const int q0 = blockIdx.x * 64;

    // Q fragments (a-frag: row = lane&15, k = (lane>>4)*8 + b), zero-pad d>=80
    bf16x8 aq[3];
    {
        int qrow = q0 + wid * 16 + l15;
        const bf16_t* qp = qkv + (long)qrow * QKV_N + h * HDIM;
#pragma unroll
        for (int ks = 0; ks < 3; ks++)
#pragma unroll
            for (int b = 0; b < 8; b++) {
                int d = ks * 32 + g * 8 + b;
                aq[ks][b] = (d < HDIM) ? qp[d] : (bf16_t)0.f;
            }
    }
    int segq[4];
#pragma unroll
    for (int r = 0; r < 4; r++) segq[r] = seg[q0 + wid * 16 + g * 4 + r];
    const int kbeg = cu[seg[q0]];
    const int kend = cu[seg[q0 + 63] + 1];

    const float scale = 0.111803398874989485f;  // 1/sqrt(80)
    float mI[4], lI[4];
    f32x4 o[5];
#pragma unroll
    for (int r = 0; r < 4; r++) { mI[r] = -1e30f; lI[r] = 0.f; }
#pragma unroll
    for (int n = 0; n < 5; n++) o[n] = (f32x4){0.f, 0.f, 0.f, 0.f};

    for (int kt = kbeg; kt < kend; kt += 64) {
        // stage K tile (vectorized 8-wide; pad d 80..95 with zeros)
        for (int c = tid; c < 64 * 12; c += 256) {
            int kr = c / 12, dc = (c % 12) * 8;
            int kg = kt + kr;
            bf16x8 v;
#pragma unroll
            for (int j = 0; j < 8; j++) v[j] = (bf16_t)0.f;
            if (dc < HDIM && kg < kend)
                v = *(const bf16x8*)(qkv + (long)kg * QKV_N + DIM + h * HDIM + dc);
            *(bf16x8*)(lK + kr * 96 + dc) = v;
        }
        // stage V transposed
        for (int c = tid; c < 64 * 10; c += 256) {
            int kl = c / 10, dc = (c % 10) * 8;
            int kg = kt + kl;
            bf16x8 v;
#pragma unroll
            for (int j = 0; j < 8; j++) v[j] = (bf16_t)0.f;
            if (kg < kend)
                v = *(const bf16x8*)(qkv + (long)kg * QKV_N + 2 * DIM + h * HDIM + dc);
#pragma unroll
            for (int j = 0; j < 8; j++) lV[(dc + j) * 64 + kl] = v[j];
        }
        __syncthreads();

        // S = Q K^T (16 x 64 per wave)
        f32x4 s[4];
#pragma unroll
        for (int n = 0; n < 4; n++) s[n] = (f32x4){0.f, 0.f, 0.f, 0.f};
#pragma unroll
        for (int n = 0; n < 4; n++)
#pragma unroll
            for (int ks = 0; ks < 3; ks++) {
                bf16x8 kf = *(const bf16x8*)(lK + (n * 16 + l15) * 96 + ks * 32 + g * 8);
                s[n] = __builtin_amdgcn_mfma_f32_16x16x32_bf16(aq[ks], kf, s[n], 0, 0, 0);
            }

        // scale + segment mask (D layout: row=(lane>>4)*4+r, col=lane&15)
        float sv[4][4];
#pragma unroll
        for (int n = 0; n < 4; n++) {
            int kg = kt + n * 16 + l15;
            int sk = (kg < kend) ? seg[kg] : -1;
#pragma unroll
            for (int r = 0; r < 4; r++)
                sv[n][r] = (sk == segq[r]) ? s[n][r] * scale : -3.0e38f;
        }

        // online softmax: row max / exp / row sum (reduce across 16 lanes)
        float nm[4], al[4], ps[4];
#pragma unroll
        for (int r = 0; r < 4; r++) {
            float x = fmaxf(fmaxf(sv[0][r], sv[1][r]), fmaxf(sv[2][r], sv[3][r]));
#pragma unroll
            for (int off = 8; off >= 1; off >>= 1) x = fmaxf(x, __shfl_xor(x, off, 64));
            nm[r] = fmaxf(mI[r], x);
            al[r] = __expf(mI[r] - nm[r]);
            ps[r] = 0.f;
        }
#pragma unroll
        for (int n = 0; n < 4; n++)
#pragma unroll
            for (int r = 0; r < 4; r++) {
                float p = __expf(sv[n][r] - nm[r]);
                ps[r] += p;
                lP[wid * 1024 + (g * 4 + r) * 64 + n * 16 + l15] = (bf16_t)p;
            }
#pragma unroll
        for (int r = 0; r < 4; r++) {
            float x = ps[r];
#pragma unroll
            for (int off = 8; off >= 1; off >>= 1) x += __shfl_xor(x, off, 64);
            lI[r] = lI[r] * al[r] + x;
            mI[r] = nm[r];
        }
#pragma unroll
        for (int n = 0; n < 5; n++)
#pragma unroll
            for (int r = 0; r < 4; r++) o[n][r] *= al[r];

        // ensure per-wave P writes land before a-frag reads
        asm volatile("s_waitcnt lgkmcnt(0)" ::: "memory");
        bf16x8 pa[2];
#pragma unroll
        for (int ks = 0; ks < 2; ks++)
            pa[ks] = *(const bf16x8*)(lP + wid * 1024 + l15 * 64 + ks * 32 + g * 8);
#pragma unroll
        for (int n = 0; n < 5; n++)
#pragma unroll
            for (int ks = 0; ks < 2; ks++) {
                bf16x8 vb = *(const bf16x8*)(lV + (n * 16 + l15) * 64 + ks * 32 + g * 8);
                o[n] = __builtin_amdgcn_mfma_f32_16x16x32_bf16(pa[ks], vb, o[n], 0, 0, 0);
            }
        __syncthreads();
    }

    // write O / l
#pragma unroll
    for (int n = 0; n < 5; n++)
#pragma unroll
        for (int r = 0; r < 4; r++) {
            int row = q0 + wid * 16 + g * 4 + r;
            out[(long)row * DIM + h * HDIM + n * 16 + l15] = (bf16_t)(o[n][r] / lI[r]);
        }
}

// ---------------- launch ----------------
extern "C" void kernel_launch(void* const* d_in, const int* in_sizes, int n_in,
                              void* d_out, int out_size, void* d_ws, size_t ws_size,
                              hipStream_t stream) {
    const float* hidden = (const float*)d_in[0];
    const float* rot    = (const float*)d_in[1];
    const int*   cu     = (const int*)d_in[2];
    const float* n1w    = (const float*)d_in[3];
    const float* n1b    = (const float*)d_in[4];
    const float* n2w    = (const float*)d_in[5];
    const float* n2b    = (const float*)d_in[6];
    const float* qkv_w  = (const float*)d_in[7];
    const float* qkv_b  = (const float*)d_in[8];
    const float* proj_w = (const float*)d_in[9];
    const float* proj_b = (const float*)d_in[10];
    const float* fc1_w  = (const float*)d_in[11];
    const float* fc1_b  = (const float*)d_in[12];
    const float* fc2_w  = (const float*)d_in[13];
    const float* fc2_b  = (const float*)d_in[14];
    float* outp = (float*)d_out;

    // workspace layout (bytes). h (fp32, 21MB) aliases qkv buffer (31.5MB) — qkv
    // is dead after attention, h is written by proj epilogue afterwards.
    char* ws = (char*)d_ws;
    bf16_t* wq   = (bf16_t*)(ws);                  //  9,830,400  qkv_w bf16
    bf16_t* wp   = (bf16_t*)(ws + 9830400);        //  3,276,800  proj_w bf16
    bf16_t* w1   = (bf16_t*)(ws + 13107200);       // 13,107,200  fc1_w bf16
    bf16_t* w2   = (bf16_t*)(ws + 26214400);       // 13,107,200  fc2_w bf16
    bf16_t* xln  = (bf16_t*)(ws + 39321600);       // 10,485,760  LN1 out / LN2 out
    bf16_t* qkvb = (bf16_t*)(ws + 49807360);       // 31,457,280  qkv bf16
    float*  hbuf = (float*)(ws + 49807360);        //   (aliases qkvb)
    bf16_t* attno= (bf16_t*)(ws + 81264640);       // 10,485,760  attention out
    bf16_t* act  = (bf16_t*)(ws + 91750400);       // 41,943,040  gelu(fc1) out
    int*    seg  = (int*)(ws + 133693440);         //     16,384  segment ids

    int ncu = in_sizes[2];

    cvt_f32_bf16<<<2048, 256, 0, stream>>>(qkv_w, wq, QKV_N * DIM);
    cvt_f32_bf16<<<1024, 256, 0, stream>>>(proj_w, wp, DIM * DIM);
    cvt_f32_bf16<<<2048, 256, 0, stream>>>(fc1_w, w1, MLP * DIM);
    cvt_f32_bf16<<<2048, 256, 0, stream>>>(fc2_w, w2, DIM * MLP);
    seg_kernel<<<(NTOK + 255) / 256, 256, 0, stream>>>(cu, ncu, seg, NTOK);

    ln_kernel<<<NTOK, 256, 0, stream>>>(hidden, n1w, n1b, xln);
    gemm_bt<0><<<dim3(QKV_N / 128, NTOK / 128), 256, 0, stream>>>(
        xln, wq, qkv_b, nullptr, qkvb, NTOK, QKV_N, DIM);
    rope_kernel<<<(NTOK * NHEADS * 40 + 255) / 256, 256, 0, stream>>>(qkvb, rot, NTOK);
    attn_kernel<<<dim3(NTOK / 64, NHEADS), 256, 0, stream>>>(qkvb, seg, cu, attno);
    gemm_bt<1><<<dim3(DIM / 128, NTOK / 128), 256, 0, stream>>>(
        attno, wp, proj_b, hidden, hbuf, NTOK, DIM, DIM);
    ln_kernel<<<NTOK, 256, 0, stream>>>(hbuf, n2w, n2b, xln);
    gemm_bt<2><<<dim3(MLP / 128, NTOK / 128), 256, 0, stream>>>(
        xln, w1, fc1_b, nullptr, act, NTOK, MLP, DIM);
    gemm_bt<1><<<dim3(DIM / 128, NTOK / 128), 256, 0, stream>>>(
        act, w2, fc2_b, hbuf, outp, NTOK, DIM, MLP);
}

// Round 2
// 528.361 us; speedup vs baseline: 1.0488x; 1.0488x over previous
//
#include <hip/hip_runtime.h>
#include <hip/hip_bf16.h>

// Qwen2VL vision block, MI355X gfx950.
// R2: GEMM staging via global_load_lds width=16 (m97 structure, linear LDS).

typedef __bf16 bf16_t;
typedef bf16_t bf16x8 __attribute__((ext_vector_type(8)));
typedef bf16_t bf16x4 __attribute__((ext_vector_type(4)));
typedef float f32x4 __attribute__((ext_vector_type(4)));

#define DIM 1280
#define NHEADS 16
#define HDIM 80
#define MLP 5120
#define NTOK 4096
#define QKV_N 3840

#define GLOAD_LDS16(gp, lp)                                                          \
    __builtin_amdgcn_global_load_lds((const __attribute__((address_space(1))) void*)(gp), \
                                     (__attribute__((address_space(3))) void*)(lp), 16, 0, 0)

// ---------------- fp32 -> bf16 conversion ----------------
__global__ void cvt_f32_bf16(const float* __restrict__ in, bf16_t* __restrict__ out, int n) {
    int i = (blockIdx.x * blockDim.x + threadIdx.x) * 4;
    int stride = gridDim.x * blockDim.x * 4;
    for (; i < n; i += stride) {
        float4 v = *(const float4*)(in + i);
        bf16x4 o;
        o[0] = (bf16_t)v.x; o[1] = (bf16_t)v.y; o[2] = (bf16_t)v.z; o[3] = (bf16_t)v.w;
        *(bf16x4*)(out + i) = o;
    }
}

// ---------------- segment ids from cu_seqlens ----------------
__global__ void seg_kernel(const int* __restrict__ cu, int ncu, int* __restrict__ seg, int n) {
    int i = blockIdx.x * blockDim.x + threadIdx.x;
    if (i >= n) return;
    int s = 0;
    for (int j = 1; j < ncu - 1; j++) if (i >= cu[j]) s = j;
    seg[i] = s;
}

// ---------------- LayerNorm (fp32 in, bf16 out), one block per row ----------------
__global__ __launch_bounds__(256) void ln_kernel(const float* __restrict__ x,
                                                 const float* __restrict__ w,
                                                 const float* __restrict__ b,
                                                 bf16_t* __restrict__ out) {
    int row = blockIdx.x;
    const float* xr = x + (long)row * DIM;
    float v[5];
    float s = 0.f, ss = 0.f;
#pragma unroll
    for (int j = 0; j < 5; j++) {
        v[j] = xr[j * 256 + threadIdx.x];
        s += v[j];
        ss += v[j] * v[j];
    }
#pragma unroll
    for (int off = 32; off > 0; off >>= 1) {
        s += __shfl_xor(s, off, 64);
        ss += __shfl_xor(ss, off, 64);
    }
    __shared__ float red[8];
    int wid = threadIdx.x >> 6;
    if ((threadIdx.x & 63) == 0) { red[wid] = s; red[wid + 4] = ss; }
    __syncthreads();
    s = red[0] + red[1] + red[2] + red[3];
    ss = red[4] + red[5] + red[6] + red[7];
    float mean = s * (1.f / DIM);
    float var = ss * (1.f / DIM) - mean * mean;
    float rstd = rsqrtf(var + 1e-6f);
    bf16_t* orow = out + (long)row * DIM;
#pragma unroll
    for (int j = 0; j < 5; j++) {
        int d = j * 256 + threadIdx.x;
        orow[d] = (bf16_t)((v[j] - mean) * rstd * w[d] + b[d]);
    }
}

// ---------------- RoPE in-place on bf16 qkv (q and k) ----------------
__global__ void rope_kernel(bf16_t* __restrict__ qkv, const float* __restrict__ rot, int n) {
    int i = blockIdx.x * blockDim.x + threadIdx.x;
    if (i >= n * NHEADS * 40) return;
    int d = i % 40;
    int hh = (i / 40) % NHEADS;
    int t = i / (40 * NHEADS);
    float r = rot[t * 40 + d];
    float c, sn;
    sincosf(r, &sn, &c);
    long base = (long)t * QKV_N + hh * HDIM;
#pragma unroll
    for (int part = 0; part < 2; part++) {
        bf16_t* p = qkv + base + part * DIM;
        float x1 = (float)p[d], x2 = (float)p[d + 40];
        p[d] = (bf16_t)(x1 * c - x2 * sn);
        p[d + 40] = (bf16_t)(x2 * c + x1 * sn);
    }
}

// ---------------- GEMM: C[M,N] = A[M,K] * B[N,K]^T + bias, epilogue variants ----
// EPI 0: out bf16 = acc + bias
// EPI 1: out f32  = res + acc + bias
// EPI 2: out bf16 = quick_gelu(acc + bias)
// m97 structure: 128x128 tile, BK=32, 4 waves (2x2), linear LDS [128][32],
// staging via global_load_lds width=16 (wave-uniform LDS base + lane*16B).
template <int EPI>
__global__ __launch_bounds__(256) void gemm_bt(const bf16_t* __restrict__ A,
                                               const bf16_t* __restrict__ B,
                                               const float* __restrict__ bias,
                                               const float* __restrict__ res,
                                               void* __restrict__ Cv,
                                               int M, int N, int K) {
    __shared__ bf16_t lA[128 * 32];
    __shared__ bf16_t lB[128 * 32];
    const int tid = threadIdx.x;
    const int lane = tid & 63;
    const int l15 = lane & 15;
    const int g = lane >> 4;
    const int wid = tid >> 6;
    const int wr = wid >> 1, wc = wid & 1;
    const int m0 = blockIdx.y * 128, n0 = blockIdx.x * 128;

    f32x4 acc[4][4];
#pragma unroll
    for (int i = 0; i < 4; i++)
#pragma unroll
        for (int j = 0; j < 4; j++) acc[i][j] = (f32x4){0.f, 0.f, 0.f, 0.f};

    // staging map: within a wave, lane i covers row (wid*16 + i/4), cols (i%4)*8..+8.
    // LDS write is wave-uniform base + lane*16B (linear [128][32] layout, no pad).
    const int lrow = lane >> 2;       // 0..15
    const int lcol = (lane & 3) * 8;  // 0,8,16,24
    const bf16_t* gA = A + (long)(m0 + wid * 16 + lrow) * K + lcol;
    const bf16_t* gB = B + (long)(n0 + wid * 16 + lrow) * K + lcol;
    bf16_t* sA0 = lA + wid * 16 * 32;
    bf16_t* sA1 = lA + (64 + wid * 16) * 32;
    bf16_t* sB0 = lB + wid * 16 * 32;
    bf16_t* sB1 = lB + (64 + wid * 16) * 32;
    const long rstep = (long)64 * K;

    for (int k0 = 0; k0 < K; k0 += 32) {
        GLOAD_LDS16(gA + k0, sA0);
        GLOAD_LDS16(gA + rstep + k0, sA1);
        GLOAD_LDS16(gB + k0, sB0);
        GLOAD_LDS16(gB + rstep + k0, sB1);
        __syncthreads();

        const int kh = g * 8;
        bf16x8 af[4], bfr[4];
#pragma unroll
        for (int m = 0; m < 4; m++)
            af[m] = *(const bf16x8*)(lA + (wr * 64 + m * 16 + l15) * 32 + kh);
#pragma unroll
        for (int n = 0; n < 4; n++)
            bfr[n] = *(const bf16x8*)(lB + (wc * 64 + n * 16 + l15) * 32 + kh);
#pragma unroll
        for (int m = 0; m < 4; m++)
#pragma unroll
            for (int n = 0; n < 4; n++)
                acc[m][n] = __builtin_amdgcn_mfma_f32_16x16x32_bf16(af[m], bfr[n], acc[m][n], 0, 0, 0);
        __syncthreads();
    }

    // epilogue: D row = (lane>>4)*4 + r, col = lane&15 (measured m89 layout)
#pragma unroll
    for (int m = 0; m < 4; m++) {
#pragma unroll
        for (int n = 0; n < 4; n++) {
            int col = n0 + wc * 64 + n * 16 + l15;
            float bv = bias[col];
#pragma unroll
            for (int r = 0; r < 4; r++) {
                int row = m0 + wr * 64 + m * 16 + g * 4 + r;
                long idx = (long)row * N + col;
                float val = acc[m][n][r] + bv;
                if (EPI == 0) {
                    ((bf16_t*)Cv)[idx] = (bf16_t)val;
                } else if (EPI == 1) {
                    ((float*)Cv)[idx] = res[idx] + val;
                } else {
                    float ge = val / (1.f + __expf(-1.702f * val));
                    ((bf16_t*)Cv)[idx] = (bf16_t)ge;
                }
            }
        }
    }
}

// ---------------- Flash attention, block-diagonal mask ----------------
__global__ __launch_bounds__(256) void attn_kernel(const bf16_t* __restrict__ qkv,
                                                   const int* __restrict__ seg,
                                                   const int* __restrict__ cu,
                                                   bf16_t* __restrict__ out) {
    __shared__ bf16_t lK[64 * 96];      // [k][d padded]
    __shared__ bf16_t lV[80 * 64];      // transposed: [d][k]
    __shared__ bf16_t lP[4 * 16 * 64];  // per-wave P tile

    const int tid = threadIdx.x;
    const int lane = tid & 63;
    const int l15 = lane & 15;
    const int g = lane >> 4;
    const int wid = tid >> 6;
    const int h = blockIdx.y;
    const int q0 = blockIdx.x * 64;

    bf16x8 aq[3];
    {
        int qrow = q0 + wid * 16 + l15;
        const bf16_t* qp = qkv + (long)qrow * QKV_N + h * HDIM;
#pragma unroll
        for (int ks = 0; ks < 3; ks++)
#pragma unroll
            for (int b = 0; b < 8; b++) {
                int d = ks * 32 + g * 8 + b;
                aq[ks][b] = (d < HDIM) ? qp[d] : (bf16_t)0.f;
            }
    }
    int segq[4];
#pragma unroll
    for (int r = 0; r < 4; r++) segq[r] = seg[q0 + wid * 16 + g * 4 + r];
    const int kbeg = cu[seg[q0]];
    const int kend = cu[seg[q0 + 63] + 1];

    const float scale = 0.111803398874989485f;  // 1/sqrt(80)
    float mI[4], lI[4];
    f32x4 o[5];
#pragma unroll
    for (int r = 0; r < 4; r++) { mI[r] = -1e30f; lI[r] = 0.f; }
#pragma unroll
    for (int n = 0; n < 5; n++) o[n] = (f32x4){0.f, 0.f, 0.f, 0.f};

    for (int kt = kbeg; kt < kend; kt += 64) {
        for (int c = tid; c < 64 * 12; c += 256) {
            int kr = c / 12, dc = (c % 12) * 8;
            int kg = kt + kr;
            bf16x8 v;
#pragma unroll
            for (int j = 0; j < 8; j++) v[j] = (bf16_t)0.f;
            if (dc < HDIM && kg < kend)
                v = *(const bf16x8*)(qkv + (long)kg * QKV_N + DIM + h * HDIM + dc);
            *(bf16x8*)(lK + kr * 96 + dc) = v;
        }
        for (int c = tid; c < 64 * 10; c += 256) {
            int kl = c / 10, dc = (c % 10) * 8;
            int kg = kt + kl;
            bf16x8 v;
#pragma unroll
            for (int j = 0; j < 8; j++) v[j] = (bf16_t)0.f;
            if (kg < kend)
                v = *(const bf16x8*)(qkv + (long)kg * QKV_N + 2 * DIM + h * HDIM + dc);
#pragma unroll
            for (int j = 0; j < 8; j++) lV[(dc + j) * 64 + kl] = v[j];
        }
        __syncthreads();

        f32x4 s[4];
#pragma unroll
        for (int n = 0; n < 4; n++) s[n] = (f32x4){0.f, 0.f, 0.f, 0.f};
#pragma unroll
        for (int n = 0; n < 4; n++)
#pragma unroll
            for (int ks = 0; ks < 3; ks++) {
                bf16x8 kf = *(const bf16x8*)(lK + (n * 16 + l15) * 96 + ks * 32 + g * 8);
                s[n] = __builtin_amdgcn_mfma_f32_16x16x32_bf16(aq[ks], kf, s[n], 0, 0, 0);
            }

        float sv[4][4];
#pragma unroll
        for (int n = 0; n < 4; n++) {
            int kg = kt + n * 16 + l15;
            int sk = (kg < kend) ? seg[kg] : -1;
#pragma unroll
            for (int r = 0; r < 4; r++)
                sv[n][r] = (sk == segq[r]) ? s[n][r] * scale : -3.0e38f;
        }

        float nm[4], al[4], ps[4];
#pragma unroll
        for (int r = 0; r < 4; r++) {
            float x = fmaxf(fmaxf(sv[0][r], sv[1][r]), fmaxf(sv[2][r], sv[3][r]));
#pragma unroll
            for (int off = 8; off >= 1; off >>= 1) x = fmaxf(x, __shfl_xor(x, off, 64));
            nm[r] = fmaxf(mI[r], x);
            al[r] = __expf(mI[r] - nm[r]);
            ps[r] = 0.f;
        }
#pragma unroll
        for (int n = 0; n < 4; n++)
#pragma unroll
            for (int r = 0; r < 4; r++) {
                float p = __expf(sv[n][r] - nm[r]);
                ps[r] += p;
                lP[wid * 1024 + (g * 4 + r) * 64 + n * 16 + l15] = (bf16_t)p;
            }
#pragma unroll
        for (int r = 0; r < 4; r++) {
            float x = ps[r];
#pragma unroll
            for (int off = 8; off >= 1; off >>= 1) x += __shfl_xor(x, off, 64);
            lI[r] = lI[r] * al[r] + x;
            mI[r] = nm[r];
        }
#pragma unroll
        for (int n = 0; n < 5; n++)
#pragma unroll
            for (int r = 0; r < 4; r++) o[n][r] *= al[r];

        asm volatile("s_waitcnt lgkmcnt(0)" ::: "memory");
        bf16x8 pa[2];
#pragma unroll
        for (int ks = 0; ks < 2; ks++)
            pa[ks] = *(const bf16x8*)(lP + wid * 1024 + l15 * 64 + ks * 32 + g * 8);
#pragma unroll
        for (int n = 0; n < 5; n++)
#pragma unroll
            for (int ks = 0; ks < 2; ks++) {
                bf16x8 vb = *(const bf16x8*)(lV + (n * 16 + l15) * 64 + ks * 32 + g * 8);
                o[n] = __builtin_amdgcn_mfma_f32_16x16x32_bf16(pa[ks], vb, o[n], 0, 0, 0);
            }
        __syncthreads();
    }

#pragma unroll
    for (int n = 0; n < 5; n++)
#pragma unroll
        for (int r = 0; r < 4; r++) {
            int row = q0 + wid * 16 + g * 4 + r;
            out[(long)row * DIM + h * HDIM + n * 16 + l15] = (bf16_t)(o[n][r] / lI[r]);
        }
}

// ---------------- launch ----------------
extern "C" void kernel_launch(void* const* d_in, const int* in_sizes, int n_in,
                              void* d_out, int out_size, void* d_ws, size_t ws_size,
                              hipStream_t stream) {
    const float* hidden = (const float*)d_in[0];
    const float* rot    = (const float*)d_in[1];
    const int*   cu     = (const int*)d_in[2];
    const float* n1w    = (const float*)d_in[3];
    const float* n1b    = (const float*)d_in[4];
    const float* n2w    = (const float*)d_in[5];
    const float* n2b    = (const float*)d_in[6];
    const float* qkv_w  = (const float*)d_in[7];
    const float* qkv_b  = (const float*)d_in[8];
    const float* proj_w = (const float*)d_in[9];
    const float* proj_b = (const float*)d_in[10];
    const float* fc1_w  = (const float*)d_in[11];
    const float* fc1_b  = (const float*)d_in[12];
    const float* fc2_w  = (const float*)d_in[13];
    const float* fc2_b  = (const float*)d_in[14];
    float* outp = (float*)d_out;

    char* ws = (char*)d_ws;
    bf16_t* wq   = (bf16_t*)(ws);                  //  9,830,400  qkv_w bf16
    bf16_t* wp   = (bf16_t*)(ws + 9830400);        //  3,276,800  proj_w bf16
    bf16_t* w1   = (bf16_t*)(ws + 13107200);       // 13,107,200  fc1_w bf16
    bf16_t* w2   = (bf16_t*)(ws + 26214400);       // 13,107,200  fc2_w bf16
    bf16_t* xln  = (bf16_t*)(ws + 39321600);       // 10,485,760  LN1 out / LN2 out
    bf16_t* qkvb = (bf16_t*)(ws + 49807360);       // 31,457,280  qkv bf16
    float*  hbuf = (float*)(ws + 49807360);        //   (aliases qkvb; qkv dead after attn)
    bf16_t* attno= (bf16_t*)(ws + 81264640);       // 10,485,760  attention out
    bf16_t* act  = (bf16_t*)(ws + 91750400);       // 41,943,040  gelu(fc1) out
    int*    seg  = (int*)(ws + 133693440);         //     16,384  segment ids

    int ncu = in_sizes[2];

    cvt_f32_bf16<<<2048, 256, 0, stream>>>(qkv_w, wq, QKV_N * DIM);
    cvt_f32_bf16<<<1024, 256, 0, stream>>>(proj_w, wp, DIM * DIM);
    cvt_f32_bf16<<<2048, 256, 0, stream>>>(fc1_w, w1, MLP * DIM);
    cvt_f32_bf16<<<2048, 256, 0, stream>>>(fc2_w, w2, DIM * MLP);
    seg_kernel<<<(NTOK + 255) / 256, 256, 0, stream>>>(cu, ncu, seg, NTOK);

    ln_kernel<<<NTOK, 256, 0, stream>>>(hidden, n1w, n1b, xln);
    gemm_bt<0><<<dim3(QKV_N / 128, NTOK / 128), 256, 0, stream>>>(
        xln, wq, qkv_b, nullptr, qkvb, NTOK, QKV_N, DIM);
    rope_kernel<<<(NTOK * NHEADS * 40 + 255) / 256, 256, 0, stream>>>(qkvb, rot, NTOK);
    attn_kernel<<<dim3(NTOK / 64, NHEADS), 256, 0, stream>>>(qkvb, seg, cu, attno);
    gemm_bt<1><<<dim3(DIM / 128, NTOK / 128), 256, 0, stream>>>(
        attno, wp, proj_b, hidden, hbuf, NTOK, DIM, DIM);
    ln_kernel<<<NTOK, 256, 0, stream>>>(hbuf, n2w, n2b, xln);
    gemm_bt<2><<<dim3(MLP / 128, NTOK / 128), 256, 0, stream>>>(
        xln, w1, fc1_b, nullptr, act, NTOK, MLP, DIM);
    gemm_bt<1><<<dim3(DIM / 128, NTOK / 128), 256, 0, stream>>>(
        act, w2, fc2_b, hbuf, outp, NTOK, DIM, MLP);
}

// Round 3
// 447.270 us; speedup vs baseline: 1.2390x; 1.1813x over previous
//
#include <hip/hip_runtime.h>
#include <hip/hip_bf16.h>

// Qwen2VL vision block, MI355X gfx950.
// R3: GEMMs -> 8-wave 256x128 BK=64 deep pipeline (3 LDS slots, counted vmcnt(6),
//     XOR-swizzled LDS via pre-swizzled global source, setprio MFMA cluster).
//     FC2 split-K x3 with f32 atomic epilogue.

typedef __bf16 bf16_t;
typedef bf16_t bf16x8 __attribute__((ext_vector_type(8)));
typedef bf16_t bf16x4 __attribute__((ext_vector_type(4)));
typedef float f32x4 __attribute__((ext_vector_type(4)));

#define DIM 1280
#define NHEADS 16
#define HDIM 80
#define MLP 5120
#define NTOK 4096
#define QKV_N 3840

#define GLOAD_LDS16(gp, lp)                                                          \
    __builtin_amdgcn_global_load_lds((const __attribute__((address_space(1))) void*)(gp), \
                                     (__attribute__((address_space(3))) void*)(lp), 16, 0, 0)

// ---------------- fp32 -> bf16 conversion ----------------
__global__ void cvt_f32_bf16(const float* __restrict__ in, bf16_t* __restrict__ out, int n) {
    int i = (blockIdx.x * blockDim.x + threadIdx.x) * 4;
    int stride = gridDim.x * blockDim.x * 4;
    for (; i < n; i += stride) {
        float4 v = *(const float4*)(in + i);
        bf16x4 o;
        o[0] = (bf16_t)v.x; o[1] = (bf16_t)v.y; o[2] = (bf16_t)v.z; o[3] = (bf16_t)v.w;
        *(bf16x4*)(out + i) = o;
    }
}

// ---------------- segment ids ----------------
__global__ void seg_kernel(const int* __restrict__ cu, int ncu, int* __restrict__ seg, int n) {
    int i = blockIdx.x * blockDim.x + threadIdx.x;
    if (i >= n) return;
    int s = 0;
    for (int j = 1; j < ncu - 1; j++) if (i >= cu[j]) s = j;
    seg[i] = s;
}

// ---------------- LayerNorm (fp32 in, bf16 out) ----------------
__global__ __launch_bounds__(256) void ln_kernel(const float* __restrict__ x,
                                                 const float* __restrict__ w,
                                                 const float* __restrict__ b,
                                                 bf16_t* __restrict__ out) {
    int row = blockIdx.x;
    const float* xr = x + (long)row * DIM;
    float v[5];
    float s = 0.f, ss = 0.f;
#pragma unroll
    for (int j = 0; j < 5; j++) {
        v[j] = xr[j * 256 + threadIdx.x];
        s += v[j];
        ss += v[j] * v[j];
    }
#pragma unroll
    for (int off = 32; off > 0; off >>= 1) {
        s += __shfl_xor(s, off, 64);
        ss += __shfl_xor(ss, off, 64);
    }
    __shared__ float red[8];
    int wid = threadIdx.x >> 6;
    if ((threadIdx.x & 63) == 0) { red[wid] = s; red[wid + 4] = ss; }
    __syncthreads();
    s = red[0] + red[1] + red[2] + red[3];
    ss = red[4] + red[5] + red[6] + red[7];
    float mean = s * (1.f / DIM);
    float var = ss * (1.f / DIM) - mean * mean;
    float rstd = rsqrtf(var + 1e-6f);
    bf16_t* orow = out + (long)row * DIM;
#pragma unroll
    for (int j = 0; j < 5; j++) {
        int d = j * 256 + threadIdx.x;
        orow[d] = (bf16_t)((v[j] - mean) * rstd * w[d] + b[d]);
    }
}

// ---------------- RoPE in-place on bf16 qkv (q and k) ----------------
__global__ void rope_kernel(bf16_t* __restrict__ qkv, const float* __restrict__ rot, int n) {
    int i = blockIdx.x * blockDim.x + threadIdx.x;
    if (i >= n * NHEADS * 40) return;
    int d = i % 40;
    int hh = (i / 40) % NHEADS;
    int t = i / (40 * NHEADS);
    float r = rot[t * 40 + d];
    float c, sn;
    sincosf(r, &sn, &c);
    long base = (long)t * QKV_N + hh * HDIM;
#pragma unroll
    for (int part = 0; part < 2; part++) {
        bf16_t* p = qkv + base + part * DIM;
        float x1 = (float)p[d], x2 = (float)p[d + 40];
        p[d] = (bf16_t)(x1 * c - x2 * sn);
        p[d + 40] = (bf16_t)(x2 * c + x1 * sn);
    }
}

// ---------------- fc2 output init: out = h + bias ----------------
__global__ void fc2_init(const float* __restrict__ h, const float* __restrict__ b,
                         float* __restrict__ out) {
    int i = blockIdx.x * blockDim.x + threadIdx.x;  // float4 index
    float4 hv = ((const float4*)h)[i];
    int c4 = (i % (DIM / 4)) * 4;
    float4 bv = *(const float4*)(b + c4);
    float4 o = {hv.x + bv.x, hv.y + bv.y, hv.z + bv.z, hv.w + bv.w};
    ((float4*)out)[i] = o;
}

// ---------------- GEMM: C[M,N] = A[M,K] * B[N,K]^T (+bias/epilogue) -----------
// 8 waves (4M x 2N), tile 256x128, BK=64. 3 LDS slots of 48KB (A 32K, B 16K).
// Deep pipeline: stage t+2 while computing t; entry wait = vmcnt(6) (t+1 stays
// in flight). LDS rows 128B, XOR-swizzled (col ^= (row&7)<<4) via pre-swizzled
// global source (linear global_load_lds dest) + same XOR on ds_read.
// EPI 0: bf16 = acc+bias | 1: f32 = res+acc+bias | 2: bf16 = qgelu(acc+bias)
// EPI 3: f32 atomicAdd(acc)  (split-K; bias handled by fc2_init)
template <int EPI>
__global__ __launch_bounds__(512, 2) void gemm8(const bf16_t* __restrict__ A,
                                                const bf16_t* __restrict__ B,
                                                const float* __restrict__ bias,
                                                const float* __restrict__ res,
                                                void* __restrict__ Cv,
                                                int M, int N, int K, int kspl) {
    __shared__ bf16_t lds[3 * 24576];  // 144 KB
    const int tid = threadIdx.x;
    const int lane = tid & 63;
    const int l15 = lane & 15;
    const int g = lane >> 4;
    const int wid = tid >> 6;   // 0..7
    const int wr = wid >> 1;    // 0..3 (M)
    const int wc = wid & 1;     // 0..1 (N)
    const int m0 = blockIdx.y * 256, n0 = blockIdx.x * 128;
    const int k0 = blockIdx.z * kspl;
    const int rem = K - k0;
    const int NT = ((rem < kspl) ? rem : kspl) >> 6;  // tiles of BK=64

    // --- staging maps (per-lane global src pre-swizzled; LDS dest linear) ---
    const bf16_t* gA[4]; int lA_[4];
#pragma unroll
    for (int j = 0; j < 4; j++) {
        int off = wid * 4096 + j * 1024 + lane * 16;   // byte off in 32KB A region
        int row = off >> 7;                            // 0..255
        int colb = (off & 127) ^ ((row & 7) << 4);     // swizzled byte col
        gA[j] = A + (long)(m0 + row) * K + k0 + (colb >> 1);
        lA_[j] = (wid * 4096 + j * 1024) >> 1;         // wave-uniform elem offset
    }
    const bf16_t* gB[2]; int lB_[2];
#pragma unroll
    for (int j = 0; j < 2; j++) {
        int off = wid * 2048 + j * 1024 + lane * 16;   // byte off in 16KB B region
        int row = off >> 7;                            // 0..127
        int colb = (off & 127) ^ ((row & 7) << 4);
        gB[j] = B + (long)(n0 + row) * K + k0 + (colb >> 1);
        lB_[j] = 16384 + ((wid * 2048 + j * 1024) >> 1);
    }

    f32x4 acc[4][4];
#pragma unroll
    for (int i = 0; i < 4; i++)
#pragma unroll
        for (int j = 0; j < 4; j++) acc[i][j] = (f32x4){0.f, 0.f, 0.f, 0.f};

    auto stage = [&](int slot, int t) {
        bf16_t* sb = lds + slot * 24576;
#pragma unroll
        for (int j = 0; j < 4; j++) GLOAD_LDS16(gA[j] + t * 64, sb + lA_[j]);
#pragma unroll
        for (int j = 0; j < 2; j++) GLOAD_LDS16(gB[j] + t * 64, sb + lB_[j]);
    };

    auto tile_body = [&](int slot) {
        const char* pA = (const char*)(lds + slot * 24576);
        const char* pB = (const char*)(lds + slot * 24576 + 16384);
        bf16x8 af[2][4], bb[2][4];
#pragma unroll
        for (int m = 0; m < 4; m++) {
            int r = wr * 64 + m * 16 + l15;
            int sw = (r & 7) << 4;
#pragma unroll
            for (int ks = 0; ks < 2; ks++)
                af[ks][m] = *(const bf16x8*)(pA + r * 128 + ((ks * 64 + g * 16) ^ sw));
        }
#pragma unroll
        for (int n = 0; n < 4; n++) {
            int r = wc * 64 + n * 16 + l15;
            int sw = (r & 7) << 4;
#pragma unroll
            for (int ks = 0; ks < 2; ks++)
                bb[ks][n] = *(const bf16x8*)(pB + r * 128 + ((ks * 64 + g * 16) ^ sw));
        }
        asm volatile("s_waitcnt lgkmcnt(0)" ::: "memory");
        __builtin_amdgcn_sched_barrier(0);
        __builtin_amdgcn_s_setprio(1);
#pragma unroll
        for (int ks = 0; ks < 2; ks++)
#pragma unroll
            for (int m = 0; m < 4; m++)
#pragma unroll
                for (int n = 0; n < 4; n++)
                    acc[m][n] = __builtin_amdgcn_mfma_f32_16x16x32_bf16(af[ks][m], bb[ks][n],
                                                                        acc[m][n], 0, 0, 0);
        __builtin_amdgcn_s_setprio(0);
    };

    // prologue: tiles 0,1 in flight
    stage(0, 0);
    stage(1, 1);

    int t = 0;
    for (; t < NT - 1; ++t) {
        // own 6 loads of tile t landed; t+1's 6 stay in flight; then barrier
        asm volatile("s_waitcnt vmcnt(6)\n\ts_barrier" ::: "memory");
        if (t + 2 < NT) stage((t + 2) % 3, t + 2);
        tile_body(t % 3);
    }
    asm volatile("s_waitcnt vmcnt(0)\n\ts_barrier" ::: "memory");
    tile_body(t % 3);

    // epilogue: D row = (lane>>4)*4 + rr, col = lane&15
#pragma unroll
    for (int m = 0; m < 4; m++)
#pragma unroll
        for (int n = 0; n < 4; n++) {
            const int col = n0 + wc * 64 + n * 16 + l15;
            const float bv = (EPI == 3) ? 0.f : bias[col];
#pragma unroll
            for (int rr = 0; rr < 4; rr++) {
                const int row = m0 + wr * 64 + m * 16 + g * 4 + rr;
                const long idx = (long)row * N + col;
                float val = acc[m][n][rr] + bv;
                if (EPI == 0) {
                    ((bf16_t*)Cv)[idx] = (bf16_t)val;
                } else if (EPI == 1) {
                    ((float*)Cv)[idx] = res[idx] + val;
                } else if (EPI == 2) {
                    float ge = val / (1.f + __expf(-1.702f * val));
                    ((bf16_t*)Cv)[idx] = (bf16_t)ge;
                } else {
                    unsafeAtomicAdd((float*)Cv + idx, acc[m][n][rr]);
                }
            }
        }
}

// ---------------- Flash attention, block-diagonal mask ----------------
__global__ __launch_bounds__(256) void attn_kernel(const bf16_t* __restrict__ qkv,
                                                   const int* __restrict__ seg,
                                                   const int* __restrict__ cu,
                                                   bf16_t* __restrict__ out) {
    __shared__ bf16_t lK[64 * 96];
    __shared__ bf16_t lV[80 * 64];
    __shared__ bf16_t lP[4 * 16 * 64];

    const int tid = threadIdx.x;
    const int lane = tid & 63;
    const int l15 = lane & 15;
    const int g = lane >> 4;
    const int wid = tid >> 6;
    const int h = blockIdx.y;
    const int q0 = blockIdx.x * 64;

    bf16x8 aq[3];
    {
        int qrow = q0 + wid * 16 + l15;
        const bf16_t* qp = qkv + (long)qrow * QKV_N + h * HDIM;
#pragma unroll
        for (int ks = 0; ks < 3; ks++)
#pragma unroll
            for (int b = 0; b < 8; b++) {
                int d = ks * 32 + g * 8 + b;
                aq[ks][b] = (d < HDIM) ? qp[d] : (bf16_t)0.f;
            }
    }
    int segq[4];
#pragma unroll
    for (int r = 0; r < 4; r++) segq[r] = seg[q0 + wid * 16 + g * 4 + r];
    const int kbeg = cu[seg[q0]];
    const int kend = cu[seg[q0 + 63] + 1];

    const float scale = 0.111803398874989485f;
    float mI[4], lI[4];
    f32x4 o[5];
#pragma unroll
    for (int r = 0; r < 4; r++) { mI[r] = -1e30f; lI[r] = 0.f; }
#pragma unroll
    for (int n = 0; n < 5; n++) o[n] = (f32x4){0.f, 0.f, 0.f, 0.f};

    for (int kt = kbeg; kt < kend; kt += 64) {
        for (int c = tid; c < 64 * 12; c += 256) {
            int kr = c / 12, dc = (c % 12) * 8;
            int kg = kt + kr;
            bf16x8 v;
#pragma unroll
            for (int j = 0; j < 8; j++) v[j] = (bf16_t)0.f;
            if (dc < HDIM && kg < kend)
                v = *(const bf16x8*)(qkv + (long)kg * QKV_N + DIM + h * HDIM + dc);
            *(bf16x8*)(lK + kr * 96 + dc) = v;
        }
        for (int c = tid; c < 64 * 10; c += 256) {
            int kl = c / 10, dc = (c % 10) * 8;
            int kg = kt + kl;
            bf16x8 v;
#pragma unroll
            for (int j = 0; j < 8; j++) v[j] = (bf16_t)0.f;
            if (kg < kend)
                v = *(const bf16x8*)(qkv + (long)kg * QKV_N + 2 * DIM + h * HDIM + dc);
#pragma unroll
            for (int j = 0; j < 8; j++) lV[(dc + j) * 64 + kl] = v[j];
        }
        __syncthreads();

        f32x4 s[4];
#pragma unroll
        for (int n = 0; n < 4; n++) s[n] = (f32x4){0.f, 0.f, 0.f, 0.f};
#pragma unroll
        for (int n = 0; n < 4; n++)
#pragma unroll
            for (int ks = 0; ks < 3; ks++) {
                bf16x8 kf = *(const bf16x8*)(lK + (n * 16 + l15) * 96 + ks * 32 + g * 8);
                s[n] = __builtin_amdgcn_mfma_f32_16x16x32_bf16(aq[ks], kf, s[n], 0, 0, 0);
            }

        float sv[4][4];
#pragma unroll
        for (int n = 0; n < 4; n++) {
            int kg = kt + n * 16 + l15;
            int sk = (kg < kend) ? seg[kg] : -1;
#pragma unroll
            for (int r = 0; r < 4; r++)
                sv[n][r] = (sk == segq[r]) ? s[n][r] * scale : -3.0e38f;
        }

        float nm[4], al[4], ps[4];
#pragma unroll
        for (int r = 0; r < 4; r++) {
            float x = fmaxf(fmaxf(sv[0][r], sv[1][r]), fmaxf(sv[2][r], sv[3][r]));
#pragma unroll
            for (int off = 8; off >= 1; off >>= 1) x = fmaxf(x, __shfl_xor(x, off, 64));
            nm[r] = fmaxf(mI[r], x);
            al[r] = __expf(mI[r] - nm[r]);
            ps[r] = 0.f;
        }
#pragma unroll
        for (int n = 0; n < 4; n++)
#pragma unroll
            for (int r = 0; r < 4; r++) {
                float p = __expf(sv[n][r] - nm[r]);
                ps[r] += p;
                lP[wid * 1024 + (g * 4 + r) * 64 + n * 16 + l15] = (bf16_t)p;
            }
#pragma unroll
        for (int r = 0; r < 4; r++) {
            float x = ps[r];
#pragma unroll
            for (int off = 8; off >= 1; off >>= 1) x += __shfl_xor(x, off, 64);
            lI[r] = lI[r] * al[r] + x;
            mI[r] = nm[r];
        }
#pragma unroll
        for (int n = 0; n < 5; n++)
#pragma unroll
            for (int r = 0; r < 4; r++) o[n][r] *= al[r];

        asm volatile("s_waitcnt lgkmcnt(0)" ::: "memory");
        bf16x8 pa[2];
#pragma unroll
        for (int ks = 0; ks < 2; ks++)
            pa[ks] = *(const bf16x8*)(lP + wid * 1024 + l15 * 64 + ks * 32 + g * 8);
#pragma unroll
        for (int n = 0; n < 5; n++)
#pragma unroll
            for (int ks = 0; ks < 2; ks++) {
                bf16x8 vb = *(const bf16x8*)(lV + (n * 16 + l15) * 64 + ks * 32 + g * 8);
                o[n] = __builtin_amdgcn_mfma_f32_16x16x32_bf16(pa[ks], vb, o[n], 0, 0, 0);
            }
        __syncthreads();
    }

#pragma unroll
    for (int n = 0; n < 5; n++)
#pragma unroll
        for (int r = 0; r < 4; r++) {
            int row = q0 + wid * 16 + g * 4 + r;
            out[(long)row * DIM + h * HDIM + n * 16 + l15] = (bf16_t)(o[n][r] / lI[r]);
        }
}

// ---------------- launch ----------------
extern "C" void kernel_launch(void* const* d_in, const int* in_sizes, int n_in,
                              void* d_out, int out_size, void* d_ws, size_t ws_size,
                              hipStream_t stream) {
    const float* hidden = (const float*)d_in[0];
    const float* rot    = (const float*)d_in[1];
    const int*   cu     = (const int*)d_in[2];
    const float* n1w    = (const float*)d_in[3];
    const float* n1b    = (const float*)d_in[4];
    const float* n2w    = (const float*)d_in[5];
    const float* n2b    = (const float*)d_in[6];
    const float* qkv_w  = (const float*)d_in[7];
    const float* qkv_b  = (const float*)d_in[8];
    const float* proj_w = (const float*)d_in[9];
    const float* proj_b = (const float*)d_in[10];
    const float* fc1_w  = (const float*)d_in[11];
    const float* fc1_b  = (const float*)d_in[12];
    const float* fc2_w  = (const float*)d_in[13];
    const float* fc2_b  = (const float*)d_in[14];
    float* outp = (float*)d_out;

    char* ws = (char*)d_ws;
    bf16_t* wq   = (bf16_t*)(ws);                  //  9,830,400  qkv_w bf16
    bf16_t* wp   = (bf16_t*)(ws + 9830400);        //  3,276,800  proj_w bf16
    bf16_t* w1   = (bf16_t*)(ws + 13107200);       // 13,107,200  fc1_w bf16
    bf16_t* w2   = (bf16_t*)(ws + 26214400);       // 13,107,200  fc2_w bf16
    bf16_t* xln  = (bf16_t*)(ws + 39321600);       // 10,485,760  LN1/LN2 out
    bf16_t* qkvb = (bf16_t*)(ws + 49807360);       // 31,457,280  qkv bf16
    float*  hbuf = (float*)(ws + 49807360);        //   (aliases qkvb; qkv dead after attn)
    bf16_t* attno= (bf16_t*)(ws + 81264640);       // 10,485,760  attention out
    bf16_t* act  = (bf16_t*)(ws + 91750400);       // 41,943,040  gelu(fc1) out
    int*    seg  = (int*)(ws + 133693440);         //     16,384  segment ids

    int ncu = in_sizes[2];

    cvt_f32_bf16<<<2048, 256, 0, stream>>>(qkv_w, wq, QKV_N * DIM);
    cvt_f32_bf16<<<1024, 256, 0, stream>>>(proj_w, wp, DIM * DIM);
    cvt_f32_bf16<<<2048, 256, 0, stream>>>(fc1_w, w1, MLP * DIM);
    cvt_f32_bf16<<<2048, 256, 0, stream>>>(fc2_w, w2, DIM * MLP);
    seg_kernel<<<(NTOK + 255) / 256, 256, 0, stream>>>(cu, ncu, seg, NTOK);

    ln_kernel<<<NTOK, 256, 0, stream>>>(hidden, n1w, n1b, xln);
    gemm8<0><<<dim3(QKV_N / 128, NTOK / 256, 1), 512, 0, stream>>>(
        xln, wq, qkv_b, nullptr, qkvb, NTOK, QKV_N, DIM, DIM);
    rope_kernel<<<(NTOK * NHEADS * 40 + 255) / 256, 256, 0, stream>>>(qkvb, rot, NTOK);
    attn_kernel<<<dim3(NTOK / 64, NHEADS), 256, 0, stream>>>(qkvb, seg, cu, attno);
    gemm8<1><<<dim3(DIM / 128, NTOK / 256, 1), 512, 0, stream>>>(
        attno, wp, proj_b, hidden, hbuf, NTOK, DIM, DIM, DIM);
    ln_kernel<<<NTOK, 256, 0, stream>>>(hbuf, n2w, n2b, xln);
    gemm8<2><<<dim3(MLP / 128, NTOK / 256, 1), 512, 0, stream>>>(
        xln, w1, fc1_b, nullptr, act, NTOK, MLP, DIM, DIM);
    fc2_init<<<NTOK * DIM / 4 / 256, 256, 0, stream>>>(hbuf, fc2_b, outp);
    gemm8<3><<<dim3(DIM / 128, NTOK / 256, 3), 512, 0, stream>>>(
        act, w2, nullptr, nullptr, outp, NTOK, DIM, MLP, 1728);
}

// Round 4
// 401.749 us; speedup vs baseline: 1.3793x; 1.1133x over previous
//
#include <hip/hip_runtime.h>
#include <hip/hip_bf16.h>

// Qwen2VL vision block, MI355X gfx950.
// R4: attention fix — prep kernel (fused RoPE + dense padded Q/K [16][4096][96]
//     + transposed V [16][80][4096]); attn LDS strides padded conflict-free
//     (lK 104, lV 72, lP 72). GEMM pipeline unchanged from R3.

typedef __bf16 bf16_t;
typedef bf16_t bf16x8 __attribute__((ext_vector_type(8)));
typedef bf16_t bf16x4 __attribute__((ext_vector_type(4)));
typedef float f32x4 __attribute__((ext_vector_type(4)));

#define DIM 1280
#define NHEADS 16
#define HDIM 80
#define MLP 5120
#define NTOK 4096
#define QKV_N 3840

#define GLOAD_LDS16(gp, lp)                                                          \
    __builtin_amdgcn_global_load_lds((const __attribute__((address_space(1))) void*)(gp), \
                                     (__attribute__((address_space(3))) void*)(lp), 16, 0, 0)

// ---------------- fp32 -> bf16 conversion ----------------
__global__ void cvt_f32_bf16(const float* __restrict__ in, bf16_t* __restrict__ out, int n) {
    int i = (blockIdx.x * blockDim.x + threadIdx.x) * 4;
    int stride = gridDim.x * blockDim.x * 4;
    for (; i < n; i += stride) {
        float4 v = *(const float4*)(in + i);
        bf16x4 o;
        o[0] = (bf16_t)v.x; o[1] = (bf16_t)v.y; o[2] = (bf16_t)v.z; o[3] = (bf16_t)v.w;
        *(bf16x4*)(out + i) = o;
    }
}

// ---------------- segment ids ----------------
__global__ void seg_kernel(const int* __restrict__ cu, int ncu, int* __restrict__ seg, int n) {
    int i = blockIdx.x * blockDim.x + threadIdx.x;
    if (i >= n) return;
    int s = 0;
    for (int j = 1; j < ncu - 1; j++) if (i >= cu[j]) s = j;
    seg[i] = s;
}

// ---------------- LayerNorm (fp32 in, bf16 out) ----------------
__global__ __launch_bounds__(256) void ln_kernel(const float* __restrict__ x,
                                                 const float* __restrict__ w,
                                                 const float* __restrict__ b,
                                                 bf16_t* __restrict__ out) {
    int row = blockIdx.x;
    const float* xr = x + (long)row * DIM;
    float v[5];
    float s = 0.f, ss = 0.f;
#pragma unroll
    for (int j = 0; j < 5; j++) {
        v[j] = xr[j * 256 + threadIdx.x];
        s += v[j];
        ss += v[j] * v[j];
    }
#pragma unroll
    for (int off = 32; off > 0; off >>= 1) {
        s += __shfl_xor(s, off, 64);
        ss += __shfl_xor(ss, off, 64);
    }
    __shared__ float red[8];
    int wid = threadIdx.x >> 6;
    if ((threadIdx.x & 63) == 0) { red[wid] = s; red[wid + 4] = ss; }
    __syncthreads();
    s = red[0] + red[1] + red[2] + red[3];
    ss = red[4] + red[5] + red[6] + red[7];
    float mean = s * (1.f / DIM);
    float var = ss * (1.f / DIM) - mean * mean;
    float rstd = rsqrtf(var + 1e-6f);
    bf16_t* orow = out + (long)row * DIM;
#pragma unroll
    for (int j = 0; j < 5; j++) {
        int d = j * 256 + threadIdx.x;
        orow[d] = (bf16_t)((v[j] - mean) * rstd * w[d] + b[d]);
    }
}

// ---------------- prep: fused RoPE + attention-friendly layouts ----------------
// Qd/Kd: [16 heads][4096 tok][96 d] bf16, d 80..95 zeroed (MFMA pad).
// Vt:    [16 heads][80 d][4096 tok] bf16.
__global__ __launch_bounds__(256) void prep_kernel(const bf16_t* __restrict__ qkv,
                                                   const float* __restrict__ rot,
                                                   bf16_t* __restrict__ Qd,
                                                   bf16_t* __restrict__ Kd,
                                                   bf16_t* __restrict__ Vt) {
    __shared__ bf16_t tv[64 * 88];  // [token][d pad 88]
    const int tid = threadIdx.x;
    const int t0 = blockIdx.x * 64;
    const int h = blockIdx.y;

    // stage V rows
    for (int c = tid; c < 64 * 10; c += 256) {
        int tl = c / 10, a = c % 10;
        bf16x8 v = *(const bf16x8*)(qkv + (long)(t0 + tl) * QKV_N + 2 * DIM + h * HDIM + a * 8);
        *(bf16x8*)(tv + tl * 88 + a * 8) = v;
    }

    // rope q,k -> Qd, Kd (4-wide chunks over d0 in [0,40))
    for (int c = tid; c < 64 * 10; c += 256) {
        int tl = c / 10, a = c % 10;
        long gq = (long)(t0 + tl) * QKV_N + h * HDIM + a * 4;
        bf16x4 q1 = *(const bf16x4*)(qkv + gq);
        bf16x4 q2 = *(const bf16x4*)(qkv + gq + 40);
        bf16x4 k1 = *(const bf16x4*)(qkv + gq + DIM);
        bf16x4 k2 = *(const bf16x4*)(qkv + gq + DIM + 40);
        float4 rv = *(const float4*)(rot + (long)(t0 + tl) * 40 + a * 4);
        float rr[4] = {rv.x, rv.y, rv.z, rv.w};
        bf16x4 oq1, oq2, ok1, ok2;
#pragma unroll
        for (int j = 0; j < 4; j++) {
            float c_, s_;
            __sincosf(rr[j], &s_, &c_);
            float x1 = (float)q1[j], x2 = (float)q2[j];
            oq1[j] = (bf16_t)(x1 * c_ - x2 * s_);
            oq2[j] = (bf16_t)(x2 * c_ + x1 * s_);
            x1 = (float)k1[j]; x2 = (float)k2[j];
            ok1[j] = (bf16_t)(x1 * c_ - x2 * s_);
            ok2[j] = (bf16_t)(x2 * c_ + x1 * s_);
        }
        long o = ((long)h * NTOK + t0 + tl) * 96 + a * 4;
        *(bf16x4*)(Qd + o) = oq1;
        *(bf16x4*)(Qd + o + 40) = oq2;
        *(bf16x4*)(Kd + o) = ok1;
        *(bf16x4*)(Kd + o + 40) = ok2;
    }
    {
        bf16x8 z;
#pragma unroll
        for (int j = 0; j < 8; j++) z[j] = (bf16_t)0.f;
        for (int c = tid; c < 64 * 2; c += 256) {
            int tl = c / 2, a = c % 2;
            long o = ((long)h * NTOK + t0 + tl) * 96 + 80 + a * 8;
            *(bf16x8*)(Qd + o) = z;
            *(bf16x8*)(Kd + o) = z;
        }
    }
    __syncthreads();

    // transpose V -> Vt
    for (int c = tid; c < 80 * 8; c += 256) {
        int d = c / 8, tc = c % 8;
        bf16x8 v;
#pragma unroll
        for (int j = 0; j < 8; j++) v[j] = tv[(tc * 8 + j) * 88 + d];
        *(bf16x8*)(Vt + ((long)h * HDIM + d) * NTOK + t0 + tc * 8) = v;
    }
}

// ---------------- fc2 output init: out = h + bias ----------------
__global__ void fc2_init(const float* __restrict__ h, const float* __restrict__ b,
                         float* __restrict__ out) {
    int i = blockIdx.x * blockDim.x + threadIdx.x;
    float4 hv = ((const float4*)h)[i];
    int c4 = (i % (DIM / 4)) * 4;
    float4 bv = *(const float4*)(b + c4);
    float4 o = {hv.x + bv.x, hv.y + bv.y, hv.z + bv.z, hv.w + bv.w};
    ((float4*)out)[i] = o;
}

// ---------------- GEMM (unchanged from R3) ----------------
template <int EPI>
__global__ __launch_bounds__(512, 2) void gemm8(const bf16_t* __restrict__ A,
                                                const bf16_t* __restrict__ B,
                                                const float* __restrict__ bias,
                                                const float* __restrict__ res,
                                                void* __restrict__ Cv,
                                                int M, int N, int K, int kspl) {
    __shared__ bf16_t lds[3 * 24576];
    const int tid = threadIdx.x;
    const int lane = tid & 63;
    const int l15 = lane & 15;
    const int g = lane >> 4;
    const int wid = tid >> 6;
    const int wr = wid >> 1;
    const int wc = wid & 1;
    const int m0 = blockIdx.y * 256, n0 = blockIdx.x * 128;
    const int k0 = blockIdx.z * kspl;
    const int rem = K - k0;
    const int NT = ((rem < kspl) ? rem : kspl) >> 6;

    const bf16_t* gA[4]; int lA_[4];
#pragma unroll
    for (int j = 0; j < 4; j++) {
        int off = wid * 4096 + j * 1024 + lane * 16;
        int row = off >> 7;
        int colb = (off & 127) ^ ((row & 7) << 4);
        gA[j] = A + (long)(m0 + row) * K + k0 + (colb >> 1);
        lA_[j] = (wid * 4096 + j * 1024) >> 1;
    }
    const bf16_t* gB[2]; int lB_[2];
#pragma unroll
    for (int j = 0; j < 2; j++) {
        int off = wid * 2048 + j * 1024 + lane * 16;
        int row = off >> 7;
        int colb = (off & 127) ^ ((row & 7) << 4);
        gB[j] = B + (long)(n0 + row) * K + k0 + (colb >> 1);
        lB_[j] = 16384 + ((wid * 2048 + j * 1024) >> 1);
    }

    f32x4 acc[4][4];
#pragma unroll
    for (int i = 0; i < 4; i++)
#pragma unroll
        for (int j = 0; j < 4; j++) acc[i][j] = (f32x4){0.f, 0.f, 0.f, 0.f};

    auto stage = [&](int slot, int t) {
        bf16_t* sb = lds + slot * 24576;
#pragma unroll
        for (int j = 0; j < 4; j++) GLOAD_LDS16(gA[j] + t * 64, sb + lA_[j]);
#pragma unroll
        for (int j = 0; j < 2; j++) GLOAD_LDS16(gB[j] + t * 64, sb + lB_[j]);
    };

    auto tile_body = [&](int slot) {
        const char* pA = (const char*)(lds + slot * 24576);
        const char* pB = (const char*)(lds + slot * 24576 + 16384);
        bf16x8 af[2][4], bb[2][4];
#pragma unroll
        for (int m = 0; m < 4; m++) {
            int r = wr * 64 + m * 16 + l15;
            int sw = (r & 7) << 4;
#pragma unroll
            for (int ks = 0; ks < 2; ks++)
                af[ks][m] = *(const bf16x8*)(pA + r * 128 + ((ks * 64 + g * 16) ^ sw));
        }
#pragma unroll
        for (int n = 0; n < 4; n++) {
            int r = wc * 64 + n * 16 + l15;
            int sw = (r & 7) << 4;
#pragma unroll
            for (int ks = 0; ks < 2; ks++)
                bb[ks][n] = *(const bf16x8*)(pB + r * 128 + ((ks * 64 + g * 16) ^ sw));
        }
        asm volatile("s_waitcnt lgkmcnt(0)" ::: "memory");
        __builtin_amdgcn_sched_barrier(0);
        __builtin_amdgcn_s_setprio(1);
#pragma unroll
        for (int ks = 0; ks < 2; ks++)
#pragma unroll
            for (int m = 0; m < 4; m++)
#pragma unroll
                for (int n = 0; n < 4; n++)
                    acc[m][n] = __builtin_amdgcn_mfma_f32_16x16x32_bf16(af[ks][m], bb[ks][n],
                                                                        acc[m][n], 0, 0, 0);
        __builtin_amdgcn_s_setprio(0);
    };

    stage(0, 0);
    stage(1, 1);

    int t = 0;
    for (; t < NT - 1; ++t) {
        asm volatile("s_waitcnt vmcnt(6)\n\ts_barrier" ::: "memory");
        if (t + 2 < NT) stage((t + 2) % 3, t + 2);
        tile_body(t % 3);
    }
    asm volatile("s_waitcnt vmcnt(0)\n\ts_barrier" ::: "memory");
    tile_body(t % 3);

#pragma unroll
    for (int m = 0; m < 4; m++)
#pragma unroll
        for (int n = 0; n < 4; n++) {
            const int col = n0 + wc * 64 + n * 16 + l15;
            const float bv = (EPI == 3) ? 0.f : bias[col];
#pragma unroll
            for (int rr = 0; rr < 4; rr++) {
                const int row = m0 + wr * 64 + m * 16 + g * 4 + rr;
                const long idx = (long)row * N + col;
                float val = acc[m][n][rr] + bv;
                if (EPI == 0) {
                    ((bf16_t*)Cv)[idx] = (bf16_t)val;
                } else if (EPI == 1) {
                    ((float*)Cv)[idx] = res[idx] + val;
                } else if (EPI == 2) {
                    float ge = val / (1.f + __expf(-1.702f * val));
                    ((bf16_t*)Cv)[idx] = (bf16_t)ge;
                } else {
                    unsafeAtomicAdd((float*)Cv + idx, acc[m][n][rr]);
                }
            }
        }
}

// ---------------- Flash attention, block-diagonal mask ----------------
// Reads dense padded Qd/Kd [h][4096][96] and transposed Vt [h][80][4096].
// LDS strides padded conflict-free: lK 104, lV 72, lP 72.
__global__ __launch_bounds__(256) void attn_kernel(const bf16_t* __restrict__ Qd,
                                                   const bf16_t* __restrict__ Kd,
                                                   const bf16_t* __restrict__ Vt,
                                                   const int* __restrict__ seg,
                                                   const int* __restrict__ cu,
                                                   bf16_t* __restrict__ out) {
    __shared__ bf16_t lK[64 * 104];
    __shared__ bf16_t lV[80 * 72];
    __shared__ bf16_t lP[4 * 16 * 72];

    const int tid = threadIdx.x;
    const int lane = tid & 63;
    const int l15 = lane & 15;
    const int g = lane >> 4;
    const int wid = tid >> 6;
    const int h = blockIdx.y;
    const int q0 = blockIdx.x * 64;

    bf16x8 aq[3];
    {
        const bf16_t* qp = Qd + ((long)h * NTOK + q0 + wid * 16 + l15) * 96;
#pragma unroll
        for (int ks = 0; ks < 3; ks++)
            aq[ks] = *(const bf16x8*)(qp + ks * 32 + g * 8);
    }
    int segq[4];
#pragma unroll
    for (int r = 0; r < 4; r++) segq[r] = seg[q0 + wid * 16 + g * 4 + r];
    const int kbeg = cu[seg[q0]];
    const int kend = cu[seg[q0 + 63] + 1];

    const float scale = 0.111803398874989485f;  // 1/sqrt(80)
    float mI[4], lI[4];
    f32x4 o[5];
#pragma unroll
    for (int r = 0; r < 4; r++) { mI[r] = -1e30f; lI[r] = 0.f; }
#pragma unroll
    for (int n = 0; n < 5; n++) o[n] = (f32x4){0.f, 0.f, 0.f, 0.f};

    for (int kt = kbeg; kt < kend; kt += 64) {
        // stage K (coalesced b128, padded stride 104)
        for (int c = tid; c < 64 * 12; c += 256) {
            int row = c / 12, c16 = c % 12;
            bf16x8 v = *(const bf16x8*)(Kd + ((long)h * NTOK + kt + row) * 96 + c16 * 8);
            *(bf16x8*)(lK + row * 104 + c16 * 8) = v;
        }
        // stage V^T (coalesced b128, padded stride 72)
        for (int c = tid; c < 80 * 8; c += 256) {
            int d = c / 8, a = c % 8;
            bf16x8 v = *(const bf16x8*)(Vt + ((long)h * HDIM + d) * NTOK + kt + a * 8);
            *(bf16x8*)(lV + d * 72 + a * 8) = v;
        }
        __syncthreads();

        // S = Q K^T (16 x 64 per wave)
        f32x4 s[4];
#pragma unroll
        for (int n = 0; n < 4; n++) s[n] = (f32x4){0.f, 0.f, 0.f, 0.f};
#pragma unroll
        for (int n = 0; n < 4; n++)
#pragma unroll
            for (int ks = 0; ks < 3; ks++) {
                bf16x8 kf = *(const bf16x8*)(lK + (n * 16 + l15) * 104 + ks * 32 + g * 8);
                s[n] = __builtin_amdgcn_mfma_f32_16x16x32_bf16(aq[ks], kf, s[n], 0, 0, 0);
            }

        // scale + segment mask
        float sv[4][4];
#pragma unroll
        for (int n = 0; n < 4; n++) {
            int kg = kt + n * 16 + l15;
            int sk = seg[kg];
#pragma unroll
            for (int r = 0; r < 4; r++)
                sv[n][r] = (sk == segq[r]) ? s[n][r] * scale : -3.0e38f;
        }

        // online softmax
        float nm[4], al[4], ps[4];
#pragma unroll
        for (int r = 0; r < 4; r++) {
            float x = fmaxf(fmaxf(sv[0][r], sv[1][r]), fmaxf(sv[2][r], sv[3][r]));
#pragma unroll
            for (int off = 8; off >= 1; off >>= 1) x = fmaxf(x, __shfl_xor(x, off, 64));
            nm[r] = fmaxf(mI[r], x);
            al[r] = __expf(mI[r] - nm[r]);
            ps[r] = 0.f;
        }
#pragma unroll
        for (int n = 0; n < 4; n++)
#pragma unroll
            for (int r = 0; r < 4; r++) {
                float p = __expf(sv[n][r] - nm[r]);
                ps[r] += p;
                lP[wid * 1152 + (g * 4 + r) * 72 + n * 16 + l15] = (bf16_t)p;
            }
#pragma unroll
        for (int r = 0; r < 4; r++) {
            float x = ps[r];
#pragma unroll
            for (int off = 8; off >= 1; off >>= 1) x += __shfl_xor(x, off, 64);
            lI[r] = lI[r] * al[r] + x;
            mI[r] = nm[r];
        }
#pragma unroll
        for (int n = 0; n < 5; n++)
#pragma unroll
            for (int r = 0; r < 4; r++) o[n][r] *= al[r];

        asm volatile("s_waitcnt lgkmcnt(0)" ::: "memory");
        bf16x8 pa[2];
#pragma unroll
        for (int ks = 0; ks < 2; ks++)
            pa[ks] = *(const bf16x8*)(lP + wid * 1152 + l15 * 72 + ks * 32 + g * 8);
#pragma unroll
        for (int n = 0; n < 5; n++)
#pragma unroll
            for (int ks = 0; ks < 2; ks++) {
                bf16x8 vb = *(const bf16x8*)(lV + (n * 16 + l15) * 72 + ks * 32 + g * 8);
                o[n] = __builtin_amdgcn_mfma_f32_16x16x32_bf16(pa[ks], vb, o[n], 0, 0, 0);
            }
        __syncthreads();
    }

#pragma unroll
    for (int n = 0; n < 5; n++)
#pragma unroll
        for (int r = 0; r < 4; r++) {
            int row = q0 + wid * 16 + g * 4 + r;
            out[(long)row * DIM + h * HDIM + n * 16 + l15] = (bf16_t)(o[n][r] / lI[r]);
        }
}

// ---------------- launch ----------------
extern "C" void kernel_launch(void* const* d_in, const int* in_sizes, int n_in,
                              void* d_out, int out_size, void* d_ws, size_t ws_size,
                              hipStream_t stream) {
    const float* hidden = (const float*)d_in[0];
    const float* rot    = (const float*)d_in[1];
    const int*   cu     = (const int*)d_in[2];
    const float* n1w    = (const float*)d_in[3];
    const float* n1b    = (const float*)d_in[4];
    const float* n2w    = (const float*)d_in[5];
    const float* n2b    = (const float*)d_in[6];
    const float* qkv_w  = (const float*)d_in[7];
    const float* qkv_b  = (const float*)d_in[8];
    const float* proj_w = (const float*)d_in[9];
    const float* proj_b = (const float*)d_in[10];
    const float* fc1_w  = (const float*)d_in[11];
    const float* fc1_b  = (const float*)d_in[12];
    const float* fc2_w  = (const float*)d_in[13];
    const float* fc2_b  = (const float*)d_in[14];
    float* outp = (float*)d_out;

    char* ws = (char*)d_ws;
    bf16_t* wq   = (bf16_t*)(ws);                  //  9,830,400  qkv_w bf16
    bf16_t* wp   = (bf16_t*)(ws + 9830400);        //  3,276,800  proj_w bf16
    bf16_t* w1   = (bf16_t*)(ws + 13107200);       // 13,107,200  fc1_w bf16
    bf16_t* w2   = (bf16_t*)(ws + 26214400);       // 13,107,200  fc2_w bf16
    bf16_t* xln  = (bf16_t*)(ws + 39321600);       // 10,485,760  LN1/LN2 out
    bf16_t* qkvb = (bf16_t*)(ws + 49807360);       // 31,457,280  qkv bf16
    float*  hbuf = (float*)(ws + 49807360);        //   (aliases qkvb; qkv dead after prep)
    bf16_t* attno= (bf16_t*)(ws + 81264640);       // 10,485,760  attention out
    bf16_t* act  = (bf16_t*)(ws + 91750400);       // 41,943,040  gelu(fc1) out
    // Qd/Kd/Vt live inside the act region (dead until FC1, which runs after attn)
    bf16_t* Qd   = (bf16_t*)(ws + 91750400);       // 12,582,912  [16][4096][96]
    bf16_t* Kd   = (bf16_t*)(ws + 104333312);      // 12,582,912  [16][4096][96]
    bf16_t* Vt   = (bf16_t*)(ws + 116916224);      // 10,485,760  [16][80][4096]
    int*    seg  = (int*)(ws + 133693440);         //     16,384  segment ids

    int ncu = in_sizes[2];

    cvt_f32_bf16<<<2048, 256, 0, stream>>>(qkv_w, wq, QKV_N * DIM);
    cvt_f32_bf16<<<1024, 256, 0, stream>>>(proj_w, wp, DIM * DIM);
    cvt_f32_bf16<<<2048, 256, 0, stream>>>(fc1_w, w1, MLP * DIM);
    cvt_f32_bf16<<<2048, 256, 0, stream>>>(fc2_w, w2, DIM * MLP);
    seg_kernel<<<(NTOK + 255) / 256, 256, 0, stream>>>(cu, ncu, seg, NTOK);

    ln_kernel<<<NTOK, 256, 0, stream>>>(hidden, n1w, n1b, xln);
    gemm8<0><<<dim3(QKV_N / 128, NTOK / 256, 1), 512, 0, stream>>>(
        xln, wq, qkv_b, nullptr, qkvb, NTOK, QKV_N, DIM, DIM);
    prep_kernel<<<dim3(NTOK / 64, NHEADS), 256, 0, stream>>>(qkvb, rot, Qd, Kd, Vt);
    attn_kernel<<<dim3(NTOK / 64, NHEADS), 256, 0, stream>>>(Qd, Kd, Vt, seg, cu, attno);
    gemm8<1><<<dim3(DIM / 128, NTOK / 256, 1), 512, 0, stream>>>(
        attno, wp, proj_b, hidden, hbuf, NTOK, DIM, DIM, DIM);
    ln_kernel<<<NTOK, 256, 0, stream>>>(hbuf, n2w, n2b, xln);
    gemm8<2><<<dim3(MLP / 128, NTOK / 256, 1), 512, 0, stream>>>(
        xln, w1, fc1_b, nullptr, act, NTOK, MLP, DIM, DIM);
    fc2_init<<<NTOK * DIM / 4 / 256, 256, 0, stream>>>(hbuf, fc2_b, outp);
    gemm8<3><<<dim3(DIM / 128, NTOK / 256, 3), 512, 0, stream>>>(
        act, w2, nullptr, nullptr, outp, NTOK, DIM, MLP, 1728);
}

// Round 5
// 378.826 us; speedup vs baseline: 1.4628x; 1.0605x over previous
//
#include <hip/hip_runtime.h>
#include <hip/hip_bf16.h>

// Qwen2VL vision block, MI355X gfx950.
// R5: gemm256 — m201 geometry (BM=256, 8 waves 2Mx4N, per-wave 128x(16NF)),
//     2-slot dbuf, counted vmcnt, XOR swizzle, XCD block swizzle.
//     FC2 split-K x2 -> f32 partials + fused reduce (atomics removed).
//     h lives in d_out (proj writes, LN2 reads, reduce accumulates).

typedef __bf16 bf16_t;
typedef bf16_t bf16x8 __attribute__((ext_vector_type(8)));
typedef bf16_t bf16x4 __attribute__((ext_vector_type(4)));
typedef float f32x4 __attribute__((ext_vector_type(4)));

#define DIM 1280
#define NHEADS 16
#define HDIM 80
#define MLP 5120
#define NTOK 4096
#define QKV_N 3840

#define GLOAD_LDS16(gp, lp)                                                          \
    __builtin_amdgcn_global_load_lds((const __attribute__((address_space(1))) void*)(gp), \
                                     (__attribute__((address_space(3))) void*)(lp), 16, 0, 0)

// ---------------- fp32 -> bf16 conversion ----------------
__global__ void cvt_f32_bf16(const float* __restrict__ in, bf16_t* __restrict__ out, int n) {
    int i = (blockIdx.x * blockDim.x + threadIdx.x) * 4;
    int stride = gridDim.x * blockDim.x * 4;
    for (; i < n; i += stride) {
        float4 v = *(const float4*)(in + i);
        bf16x4 o;
        o[0] = (bf16_t)v.x; o[1] = (bf16_t)v.y; o[2] = (bf16_t)v.z; o[3] = (bf16_t)v.w;
        *(bf16x4*)(out + i) = o;
    }
}

// ---------------- segment ids ----------------
__global__ void seg_kernel(const int* __restrict__ cu, int ncu, int* __restrict__ seg, int n) {
    int i = blockIdx.x * blockDim.x + threadIdx.x;
    if (i >= n) return;
    int s = 0;
    for (int j = 1; j < ncu - 1; j++) if (i >= cu[j]) s = j;
    seg[i] = s;
}

// ---------------- LayerNorm (fp32 in, bf16 out) ----------------
__global__ __launch_bounds__(256) void ln_kernel(const float* __restrict__ x,
                                                 const float* __restrict__ w,
                                                 const float* __restrict__ b,
                                                 bf16_t* __restrict__ out) {
    int row = blockIdx.x;
    const float* xr = x + (long)row * DIM;
    float v[5];
    float s = 0.f, ss = 0.f;
#pragma unroll
    for (int j = 0; j < 5; j++) {
        v[j] = xr[j * 256 + threadIdx.x];
        s += v[j];
        ss += v[j] * v[j];
    }
#pragma unroll
    for (int off = 32; off > 0; off >>= 1) {
        s += __shfl_xor(s, off, 64);
        ss += __shfl_xor(ss, off, 64);
    }
    __shared__ float red[8];
    int wid = threadIdx.x >> 6;
    if ((threadIdx.x & 63) == 0) { red[wid] = s; red[wid + 4] = ss; }
    __syncthreads();
    s = red[0] + red[1] + red[2] + red[3];
    ss = red[4] + red[5] + red[6] + red[7];
    float mean = s * (1.f / DIM);
    float var = ss * (1.f / DIM) - mean * mean;
    float rstd = rsqrtf(var + 1e-6f);
    bf16_t* orow = out + (long)row * DIM;
#pragma unroll
    for (int j = 0; j < 5; j++) {
        int d = j * 256 + threadIdx.x;
        orow[d] = (bf16_t)((v[j] - mean) * rstd * w[d] + b[d]);
    }
}

// ---------------- prep: fused RoPE + attention-friendly layouts ----------------
__global__ __launch_bounds__(256) void prep_kernel(const bf16_t* __restrict__ qkv,
                                                   const float* __restrict__ rot,
                                                   bf16_t* __restrict__ Qd,
                                                   bf16_t* __restrict__ Kd,
                                                   bf16_t* __restrict__ Vt) {
    __shared__ bf16_t tv[64 * 88];
    const int tid = threadIdx.x;
    const int t0 = blockIdx.x * 64;
    const int h = blockIdx.y;

    for (int c = tid; c < 64 * 10; c += 256) {
        int tl = c / 10, a = c % 10;
        bf16x8 v = *(const bf16x8*)(qkv + (long)(t0 + tl) * QKV_N + 2 * DIM + h * HDIM + a * 8);
        *(bf16x8*)(tv + tl * 88 + a * 8) = v;
    }

    for (int c = tid; c < 64 * 10; c += 256) {
        int tl = c / 10, a = c % 10;
        long gq = (long)(t0 + tl) * QKV_N + h * HDIM + a * 4;
        bf16x4 q1 = *(const bf16x4*)(qkv + gq);
        bf16x4 q2 = *(const bf16x4*)(qkv + gq + 40);
        bf16x4 k1 = *(const bf16x4*)(qkv + gq + DIM);
        bf16x4 k2 = *(const bf16x4*)(qkv + gq + DIM + 40);
        float4 rv = *(const float4*)(rot + (long)(t0 + tl) * 40 + a * 4);
        float rr[4] = {rv.x, rv.y, rv.z, rv.w};
        bf16x4 oq1, oq2, ok1, ok2;
#pragma unroll
        for (int j = 0; j < 4; j++) {
            float c_, s_;
            __sincosf(rr[j], &s_, &c_);
            float x1 = (float)q1[j], x2 = (float)q2[j];
            oq1[j] = (bf16_t)(x1 * c_ - x2 * s_);
            oq2[j] = (bf16_t)(x2 * c_ + x1 * s_);
            x1 = (float)k1[j]; x2 = (float)k2[j];
            ok1[j] = (bf16_t)(x1 * c_ - x2 * s_);
            ok2[j] = (bf16_t)(x2 * c_ + x1 * s_);
        }
        long o = ((long)h * NTOK + t0 + tl) * 96 + a * 4;
        *(bf16x4*)(Qd + o) = oq1;
        *(bf16x4*)(Qd + o + 40) = oq2;
        *(bf16x4*)(Kd + o) = ok1;
        *(bf16x4*)(Kd + o + 40) = ok2;
    }
    {
        bf16x8 z;
#pragma unroll
        for (int j = 0; j < 8; j++) z[j] = (bf16_t)0.f;
        for (int c = tid; c < 64 * 2; c += 256) {
            int tl = c / 2, a = c % 2;
            long o = ((long)h * NTOK + t0 + tl) * 96 + 80 + a * 8;
            *(bf16x8*)(Qd + o) = z;
            *(bf16x8*)(Kd + o) = z;
        }
    }
    __syncthreads();

    for (int c = tid; c < 80 * 8; c += 256) {
        int d = c / 8, tc = c % 8;
        bf16x8 v;
#pragma unroll
        for (int j = 0; j < 8; j++) v[j] = tv[(tc * 8 + j) * 88 + d];
        *(bf16x8*)(Vt + ((long)h * HDIM + d) * NTOK + t0 + tc * 8) = v;
    }
}

// ---------------- fc2 reduce: out += bias + p0 + p1 ----------------
__global__ void fc2_reduce(const float* __restrict__ p, const float* __restrict__ b,
                           float* __restrict__ out) {
    long i = (long)blockIdx.x * blockDim.x + threadIdx.x;  // float4 index
    float4 o = ((const float4*)out)[i];
    float4 a0 = ((const float4*)p)[i];
    float4 a1 = ((const float4*)p)[i + (long)NTOK * DIM / 4];
    int c4 = (int)(i % (DIM / 4)) * 4;
    float4 bv = *(const float4*)(b + c4);
    o.x += a0.x + a1.x + bv.x;
    o.y += a0.y + a1.y + bv.y;
    o.z += a0.z + a1.z + bv.z;
    o.w += a0.w + a1.w + bv.w;
    ((float4*)out)[i] = o;
}

// ---------------- GEMM: C[M,N] = A[M,K] * B[N,K]^T (+epilogue) -----------------
// BM=256, BN=64*NF (NF=5 -> 320, NF=4 -> 256), BK=64. 8 waves (2M x 4N),
// per-wave 128 x 16*NF (8 x NF frags of 16x16x32). 2-slot LDS double buffer,
// counted vmcnt(4+NF) at entry (drains only on final tile). Rows 128B,
// XOR swizzle (col ^= (row&7)<<4) via pre-swizzled global source.
// EPI 0: bf16 = acc+bias | 1: f32 = res+acc+bias | 2: bf16 = qgelu(acc+bias)
// EPI 3: f32 raw store to Cv + z*M*N (split-K partial)
template <int EPI, int NF>
__global__ __launch_bounds__(512, 2) void gemm256(const bf16_t* __restrict__ A,
                                                  const bf16_t* __restrict__ B,
                                                  const float* __restrict__ bias,
                                                  const float* __restrict__ res,
                                                  void* __restrict__ Cv,
                                                  int M, int N, int K, int kspl) {
    constexpr int SLOTB = 32768 + NF * 8192;  // bytes: A 32KB + B NF*8KB
    __shared__ char lds[2 * SLOTB];
    const int tid = threadIdx.x;
    const int lane = tid & 63;
    const int l15 = lane & 15;
    const int g = lane >> 4;
    const int wid = tid >> 6;   // 0..7
    const int wr = wid >> 2;    // 0..1 (M)
    const int wc = wid & 3;     // 0..3 (N)

    // XCD-bijective block swizzle (all grids have nwg % 8 == 0)
    const int nx = gridDim.x;
    const int id = blockIdx.y * nx + blockIdx.x;
    const int cpx = (nx * gridDim.y) >> 3;
    const int sid = (id & 7) * cpx + (id >> 3);
    const int m0 = (sid / nx) * 256;
    const int n0 = (sid % nx) * (NF * 64);
    const int k0 = blockIdx.z * kspl;
    const int NT = kspl >> 6;

    // staging maps: per-lane global src pre-swizzled; LDS dest linear
    const bf16_t* gA[4]; int lAo[4];
#pragma unroll
    for (int j = 0; j < 4; j++) {
        int off = j * 8192 + tid * 16;
        int row = off >> 7;
        int cb = (off & 127) ^ ((row & 7) << 4);
        gA[j] = A + (long)(m0 + row) * K + k0 + (cb >> 1);
        lAo[j] = j * 8192 + wid * 1024;
    }
    const bf16_t* gB[NF]; int lBo[NF];
#pragma unroll
    for (int j = 0; j < NF; j++) {
        int off = j * 8192 + tid * 16;
        int row = off >> 7;
        int cb = (off & 127) ^ ((row & 7) << 4);
        gB[j] = B + (long)(n0 + row) * K + k0 + (cb >> 1);
        lBo[j] = 32768 + j * 8192 + wid * 1024;
    }

    f32x4 acc[8][NF];
#pragma unroll
    for (int i = 0; i < 8; i++)
#pragma unroll
        for (int j = 0; j < NF; j++) acc[i][j] = (f32x4){0.f, 0.f, 0.f, 0.f};

    auto stage = [&](int slot, int t) {
        char* sb = lds + slot * SLOTB;
#pragma unroll
        for (int j = 0; j < 4; j++) GLOAD_LDS16(gA[j] + t * 64, sb + lAo[j]);
#pragma unroll
        for (int j = 0; j < NF; j++) GLOAD_LDS16(gB[j] + t * 64, sb + lBo[j]);
    };

    auto tile_body = [&](int slot) {
        const char* pA = lds + slot * SLOTB;
        const char* pB = pA + 32768;
#pragma unroll
        for (int ks = 0; ks < 2; ks++) {
            bf16x8 af[8], bb[NF];
#pragma unroll
            for (int n = 0; n < NF; n++) {
                int r = wc * (NF * 16) + n * 16 + l15;
                bb[n] = *(const bf16x8*)(pB + r * 128 + ((ks * 64 + g * 16) ^ ((r & 7) << 4)));
            }
#pragma unroll
            for (int m = 0; m < 8; m++) {
                int r = wr * 128 + m * 16 + l15;
                af[m] = *(const bf16x8*)(pA + r * 128 + ((ks * 64 + g * 16) ^ ((r & 7) << 4)));
            }
            asm volatile("s_waitcnt lgkmcnt(0)" ::: "memory");
            __builtin_amdgcn_sched_barrier(0);
            __builtin_amdgcn_s_setprio(1);
#pragma unroll
            for (int m = 0; m < 8; m++)
#pragma unroll
                for (int n = 0; n < NF; n++)
                    acc[m][n] = __builtin_amdgcn_mfma_f32_16x16x32_bf16(af[m], bb[n],
                                                                        acc[m][n], 0, 0, 0);
            __builtin_amdgcn_s_setprio(0);
        }
    };

    stage(0, 0);
    stage(1, 1);

    for (int t = 0; t < NT; ++t) {
        if (t < NT - 1) {
            if constexpr (NF == 4)
                asm volatile("s_waitcnt vmcnt(8)\n\ts_barrier" ::: "memory");
            else
                asm volatile("s_waitcnt vmcnt(9)\n\ts_barrier" ::: "memory");
        } else {
            asm volatile("s_waitcnt vmcnt(0)\n\ts_barrier" ::: "memory");
        }
        tile_body(t & 1);
        if (t + 2 < NT) {
            asm volatile("s_barrier" ::: "memory");
            stage(t & 1, t + 2);
        }
    }

    // epilogue: D row = (lane>>4)*4 + rr, col = lane&15
#pragma unroll
    for (int m = 0; m < 8; m++)
#pragma unroll
        for (int n = 0; n < NF; n++) {
            const int col = n0 + wc * (NF * 16) + n * 16 + l15;
            const float bv = (EPI == 3) ? 0.f : bias[col];
#pragma unroll
            for (int rr = 0; rr < 4; rr++) {
                const int row = m0 + wr * 128 + m * 16 + g * 4 + rr;
                const long idx = (long)row * N + col;
                float val = acc[m][n][rr] + bv;
                if (EPI == 0) {
                    ((bf16_t*)Cv)[idx] = (bf16_t)val;
                } else if (EPI == 1) {
                    ((float*)Cv)[idx] = res[idx] + val;
                } else if (EPI == 2) {
                    float ge = val / (1.f + __expf(-1.702f * val));
                    ((bf16_t*)Cv)[idx] = (bf16_t)ge;
                } else {
                    ((float*)Cv)[(long)blockIdx.z * M * N + idx] = val;
                }
            }
        }
}

// ---------------- Flash attention, block-diagonal mask ----------------
__global__ __launch_bounds__(256) void attn_kernel(const bf16_t* __restrict__ Qd,
                                                   const bf16_t* __restrict__ Kd,
                                                   const bf16_t* __restrict__ Vt,
                                                   const int* __restrict__ seg,
                                                   const int* __restrict__ cu,
                                                   bf16_t* __restrict__ out) {
    __shared__ bf16_t lK[64 * 104];
    __shared__ bf16_t lV[80 * 72];
    __shared__ bf16_t lP[4 * 16 * 72];

    const int tid = threadIdx.x;
    const int lane = tid & 63;
    const int l15 = lane & 15;
    const int g = lane >> 4;
    const int wid = tid >> 6;
    const int h = blockIdx.y;
    const int q0 = blockIdx.x * 64;

    bf16x8 aq[3];
    {
        const bf16_t* qp = Qd + ((long)h * NTOK + q0 + wid * 16 + l15) * 96;
#pragma unroll
        for (int ks = 0; ks < 3; ks++)
            aq[ks] = *(const bf16x8*)(qp + ks * 32 + g * 8);
    }
    int segq[4];
#pragma unroll
    for (int r = 0; r < 4; r++) segq[r] = seg[q0 + wid * 16 + g * 4 + r];
    const int kbeg = cu[seg[q0]];
    const int kend = cu[seg[q0 + 63] + 1];

    const float scale = 0.111803398874989485f;  // 1/sqrt(80)
    float mI[4], lI[4];
    f32x4 o[5];
#pragma unroll
    for (int r = 0; r < 4; r++) { mI[r] = -1e30f; lI[r] = 0.f; }
#pragma unroll
    for (int n = 0; n < 5; n++) o[n] = (f32x4){0.f, 0.f, 0.f, 0.f};

    for (int kt = kbeg; kt < kend; kt += 64) {
        for (int c = tid; c < 64 * 12; c += 256) {
            int row = c / 12, c16 = c % 12;
            bf16x8 v = *(const bf16x8*)(Kd + ((long)h * NTOK + kt + row) * 96 + c16 * 8);
            *(bf16x8*)(lK + row * 104 + c16 * 8) = v;
        }
        for (int c = tid; c < 80 * 8; c += 256) {
            int d = c / 8, a = c % 8;
            bf16x8 v = *(const bf16x8*)(Vt + ((long)h * HDIM + d) * NTOK + kt + a * 8);
            *(bf16x8*)(lV + d * 72 + a * 8) = v;
        }
        __syncthreads();

        f32x4 s[4];
#pragma unroll
        for (int n = 0; n < 4; n++) s[n] = (f32x4){0.f, 0.f, 0.f, 0.f};
#pragma unroll
        for (int n = 0; n < 4; n++)
#pragma unroll
            for (int ks = 0; ks < 3; ks++) {
                bf16x8 kf = *(const bf16x8*)(lK + (n * 16 + l15) * 104 + ks * 32 + g * 8);
                s[n] = __builtin_amdgcn_mfma_f32_16x16x32_bf16(aq[ks], kf, s[n], 0, 0, 0);
            }

        float sv[4][4];
#pragma unroll
        for (int n = 0; n < 4; n++) {
            int kg = kt + n * 16 + l15;
            int sk = seg[kg];
#pragma unroll
            for (int r = 0; r < 4; r++)
                sv[n][r] = (sk == segq[r]) ? s[n][r] * scale : -3.0e38f;
        }

        float nm[4], al[4], ps[4];
#pragma unroll
        for (int r = 0; r < 4; r++) {
            float x = fmaxf(fmaxf(sv[0][r], sv[1][r]), fmaxf(sv[2][r], sv[3][r]));
#pragma unroll
            for (int off = 8; off >= 1; off >>= 1) x = fmaxf(x, __shfl_xor(x, off, 64));
            nm[r] = fmaxf(mI[r], x);
            al[r] = __expf(mI[r] - nm[r]);
            ps[r] = 0.f;
        }
#pragma unroll
        for (int n = 0; n < 4; n++)
#pragma unroll
            for (int r = 0; r < 4; r++) {
                float p = __expf(sv[n][r] - nm[r]);
                ps[r] += p;
                lP[wid * 1152 + (g * 4 + r) * 72 + n * 16 + l15] = (bf16_t)p;
            }
#pragma unroll
        for (int r = 0; r < 4; r++) {
            float x = ps[r];
#pragma unroll
            for (int off = 8; off >= 1; off >>= 1) x += __shfl_xor(x, off, 64);
            lI[r] = lI[r] * al[r] + x;
            mI[r] = nm[r];
        }
#pragma unroll
        for (int n = 0; n < 5; n++)
#pragma unroll
            for (int r = 0; r < 4; r++) o[n][r] *= al[r];

        asm volatile("s_waitcnt lgkmcnt(0)" ::: "memory");
        bf16x8 pa[2];
#pragma unroll
        for (int ks = 0; ks < 2; ks++)
            pa[ks] = *(const bf16x8*)(lP + wid * 1152 + l15 * 72 + ks * 32 + g * 8);
#pragma unroll
        for (int n = 0; n < 5; n++)
#pragma unroll
            for (int ks = 0; ks < 2; ks++) {
                bf16x8 vb = *(const bf16x8*)(lV + (n * 16 + l15) * 72 + ks * 32 + g * 8);
                o[n] = __builtin_amdgcn_mfma_f32_16x16x32_bf16(pa[ks], vb, o[n], 0, 0, 0);
            }
        __syncthreads();
    }

#pragma unroll
    for (int n = 0; n < 5; n++)
#pragma unroll
        for (int r = 0; r < 4; r++) {
            int row = q0 + wid * 16 + g * 4 + r;
            out[(long)row * DIM + h * HDIM + n * 16 + l15] = (bf16_t)(o[n][r] / lI[r]);
        }
}

// ---------------- launch ----------------
extern "C" void kernel_launch(void* const* d_in, const int* in_sizes, int n_in,
                              void* d_out, int out_size, void* d_ws, size_t ws_size,
                              hipStream_t stream) {
    const float* hidden = (const float*)d_in[0];
    const float* rot    = (const float*)d_in[1];
    const int*   cu     = (const int*)d_in[2];
    const float* n1w    = (const float*)d_in[3];
    const float* n1b    = (const float*)d_in[4];
    const float* n2w    = (const float*)d_in[5];
    const float* n2b    = (const float*)d_in[6];
    const float* qkv_w  = (const float*)d_in[7];
    const float* qkv_b  = (const float*)d_in[8];
    const float* proj_w = (const float*)d_in[9];
    const float* proj_b = (const float*)d_in[10];
    const float* fc1_w  = (const float*)d_in[11];
    const float* fc1_b  = (const float*)d_in[12];
    const float* fc2_w  = (const float*)d_in[13];
    const float* fc2_b  = (const float*)d_in[14];
    float* outp = (float*)d_out;

    // workspace layout (bytes), total 133,709,824 (same footprint as R4):
    char* ws = (char*)d_ws;
    bf16_t* w2   = (bf16_t*)(ws);                  // [0,13107200)      live: cvt->FC2
    bf16_t* w1   = (bf16_t*)(ws + 13107200);       // [13.1M,26.2M)     cvt->FC1
    bf16_t* wp   = (bf16_t*)(ws + 26214400);       // [26.2M,29.5M)     cvt->proj
    bf16_t* wq   = (bf16_t*)(ws + 29491200);       // [29.5M,39.3M)     cvt->QKV
    bf16_t* xln  = (bf16_t*)(ws + 39321600);       // [39.3M,49.8M)     LN1->QKV, LN2->FC1
    bf16_t* qkvb = (bf16_t*)(ws + 49807360);       // [49.8M,81.3M)     QKV->prep
    bf16_t* Qd   = (bf16_t*)(ws + 81264640);       // [81.3M,93.8M)     prep->attn
    bf16_t* Kd   = (bf16_t*)(ws + 93847552);       // [93.8M,106.4M)    prep->attn
    bf16_t* Vt   = (bf16_t*)(ws + 106430464);      // [106.4M,116.9M)   prep->attn
    bf16_t* attno= (bf16_t*)(ws + 116916224);      // [116.9M,127.4M)   attn->proj
    bf16_t* act  = (bf16_t*)(ws + 49807360);       // [49.8M,91.75M)    FC1->FC2 (over qkvb+Qd, dead)
    float*  p01  = (float*)(ws + 91750400);        // [91.75M,133.69M)  FC2 partials (over Kd/Vt/attno, dead)
    int*    seg  = (int*)(ws + 133693440);         // 16KB
    // h (f32 4096x1280) lives in d_out: proj writes, LN2 reads, reduce accumulates.

    int ncu = in_sizes[2];

    cvt_f32_bf16<<<2048, 256, 0, stream>>>(qkv_w, wq, QKV_N * DIM);
    cvt_f32_bf16<<<1024, 256, 0, stream>>>(proj_w, wp, DIM * DIM);
    cvt_f32_bf16<<<2048, 256, 0, stream>>>(fc1_w, w1, MLP * DIM);
    cvt_f32_bf16<<<2048, 256, 0, stream>>>(fc2_w, w2, DIM * MLP);
    seg_kernel<<<(NTOK + 255) / 256, 256, 0, stream>>>(cu, ncu, seg, NTOK);

    ln_kernel<<<NTOK, 256, 0, stream>>>(hidden, n1w, n1b, xln);
    // QKV: 4096x3840x1280, BN=320 -> grid 12x16 = 192 blocks
    gemm256<0, 5><<<dim3(QKV_N / 320, NTOK / 256, 1), 512, 0, stream>>>(
        xln, wq, qkv_b, nullptr, qkvb, NTOK, QKV_N, DIM, DIM);
    prep_kernel<<<dim3(NTOK / 64, NHEADS), 256, 0, stream>>>(qkvb, rot, Qd, Kd, Vt);
    attn_kernel<<<dim3(NTOK / 64, NHEADS), 256, 0, stream>>>(Qd, Kd, Vt, seg, cu, attno);
    // proj: 4096x1280x1280, BN=256 -> grid 5x16 = 80 blocks; writes h into d_out
    gemm256<1, 4><<<dim3(DIM / 256, NTOK / 256, 1), 512, 0, stream>>>(
        attno, wp, proj_b, hidden, outp, NTOK, DIM, DIM, DIM);
    ln_kernel<<<NTOK, 256, 0, stream>>>(outp, n2w, n2b, xln);
    // FC1: 4096x5120x1280, BN=320 -> grid 16x16 = 256 blocks
    gemm256<2, 5><<<dim3(MLP / 320, NTOK / 256, 1), 512, 0, stream>>>(
        xln, w1, fc1_b, nullptr, act, NTOK, MLP, DIM, DIM);
    // FC2: 4096x1280x5120, BN=256, split-K x2 -> grid 5x16x2 = 160 blocks
    gemm256<3, 4><<<dim3(DIM / 256, NTOK / 256, 2), 512, 0, stream>>>(
        act, w2, nullptr, nullptr, p01, NTOK, DIM, MLP, 2560);
    fc2_reduce<<<NTOK * DIM / 4 / 256, 256, 0, stream>>>(p01, fc2_b, outp);
}